// Round 12
// baseline (287.603 us; speedup 1.0000x reference)
//
#include <hip/hip_runtime.h>
#include <hip/hip_bf16.h>
#include <math.h>

#define N_NODES 100000
#define N_EDGES 600000
#define H 128
#define LH 256
#define CDIM 8
#define NB_STATS 64
#define NT128 ((N_NODES + 127) / 128)   // 782 (128-row tiles, fused kernel)

typedef __attribute__((ext_vector_type(8))) short short8;
typedef __attribute__((ext_vector_type(4))) float floatx4;

// ------------- workspace layout (4-byte words) -------------
#define OFF_PART   0
#define OFF_PARAMS 704
#define OFF_DEG    712
#define OFF_ROWPTR (OFF_DEG + N_NODES)
#define OFF_BSUMS  (OFF_ROWPTR + N_NODES)
#define OFF_H0     (OFF_BSUMS + 128)            // N*4 fp32 (float4 rows)
#define OFF_AGG1   (OFF_H0 + N_NODES*4)         // (unused, kept for layout)
#define OFF_CSR    (OFF_AGG1 + N_NODES*4)
#define OFF_WPK2   (OFF_CSR + N_EDGES)          // 32768 bf16 = 16384 words
#define OFF_WPK1   (OFF_WPK2 + 16384)           // 32768 bf16
#define OFF_W2PK   (OFF_WPK1 + 16384)           // 4096 bf16 = 2048 words
#define OFF_XB     (OFF_W2PK + 2048)            // N*256 bf16 = 12.8M words

__device__ __forceinline__ float rot_c() { return cosf(1.57079632679489661923f); }
__device__ __forceinline__ float rot_s() { return sinf(1.57079632679489661923f); }
__device__ __forceinline__ float bfhi(unsigned v) { return __uint_as_float(v & 0xffff0000u); }
__device__ __forceinline__ float bflo(unsigned v) { return __uint_as_float(v << 16); }
__device__ __forceinline__ unsigned short bfu(float f) {
    __hip_bfloat16 h = __float2bfloat16(f);
    return *(unsigned short*)&h;
}
// fast tanh: 1 - 2/(e^{2x}+1). Exact at +-inf (rcp(inf)=0), rel err ~1e-6,
// far below bf16 quantization (~4e-3). ~5 VALU ops vs ~40 for libm tanhf.
__device__ __forceinline__ float ftanh(float x) {
    float e = __expf(2.0f * x);
    return 1.0f - 2.0f * __builtin_amdgcn_rcpf(e + 1.0f);
}

// ---------------- stats partial (also zeroes deg) ----------------
__global__ void stats_partial_k(const float* __restrict__ x, float* __restrict__ part,
                                int* __restrict__ deg) {
    const float c = rot_c(), sn = rot_s();
    float mn0 = INFINITY, mx0 = -INFINITY, mn1 = INFINITY, mx1 = -INFINITY;
    float s0 = 0.f, s1 = 0.f, sr0 = 0.f, sr1 = 0.f;
    float mxr0 = -INFINITY, mxr1 = -INFINITY, mxa = -INFINITY;
    for (int i = blockIdx.x * blockDim.x + threadIdx.x; i < N_NODES;
         i += gridDim.x * blockDim.x) {
        deg[i] = 0;
        float x0 = x[3*i], x1 = x[3*i+1], a = x[3*i+2];
        float r0 = c*x0 - sn*x1;
        float r1 = sn*x0 + c*x1;
        mn0 = fminf(mn0, x0); mx0 = fmaxf(mx0, x0);
        mn1 = fminf(mn1, x1); mx1 = fmaxf(mx1, x1);
        s0 += x0; s1 += x1; sr0 += r0; sr1 += r1;
        mxr0 = fmaxf(mxr0, r0); mxr1 = fmaxf(mxr1, r1);
        mxa = fmaxf(mxa, a);
    }
    __shared__ float red[256];
    float vals[11] = {mn0, mx0, mn1, mx1, s0, s1, sr0, sr1, mxr0, mxr1, mxa};
    const int ops[11] = {0,1,0,1,2,2,2,2,1,1,1};
    for (int v = 0; v < 11; v++) {
        red[threadIdx.x] = vals[v];
        __syncthreads();
        for (int s = 128; s > 0; s >>= 1) {
            if ((int)threadIdx.x < s) {
                float a = red[threadIdx.x], b = red[threadIdx.x + s];
                red[threadIdx.x] = (ops[v]==0) ? fminf(a,b) : (ops[v]==1) ? fmaxf(a,b) : (a+b);
            }
            __syncthreads();
        }
        if (threadIdx.x == 0) part[blockIdx.x * 11 + v] = red[0];
        __syncthreads();
    }
}

// ---------------- normalize (+ final stats reduce + weight pre-pack) ------
__global__ __launch_bounds__(256) void normalize_k(const float* __restrict__ x,
        const float* __restrict__ part, float4* __restrict__ h0,
        const float* __restrict__ Wl2, const float* __restrict__ Wr2,
        const float* __restrict__ W1, const float* __restrict__ W2,
        __hip_bfloat16* __restrict__ Wpk2, __hip_bfloat16* __restrict__ Wpk1,
        __hip_bfloat16* __restrict__ W2pk) {
    __shared__ float res[11];
    int tid = threadIdx.x;
    if (tid < 64) {
        const int ops[11] = {0,1,0,1,2,2,2,2,1,1,1};
        for (int v = 0; v < 11; v++) {
            float val = part[tid * 11 + v];
            #pragma unroll
            for (int off = 32; off > 0; off >>= 1) {
                float o = __shfl_down(val, off);
                val = (ops[v]==0) ? fminf(val,o) : (ops[v]==1) ? fmaxf(val,o) : (val+o);
            }
            if (tid == 0) res[v] = val;
        }
    }
    __syncthreads();
    int rotate = (res[3] - res[2]) > (res[1] - res[0]);
    float mean0 = (rotate ? res[6] : res[4]) / (float)N_NODES;
    float mean1 = (rotate ? res[7] : res[5]) / (float)N_NODES;
    float imx0  = 1.0f / (rotate ? res[8] : res[1]);
    float imx1  = 1.0f / (rotate ? res[9] : res[3]);
    float imxa  = 1.0f / res[10];

    int i = blockIdx.x * blockDim.x + tid;
    if (i < N_NODES) {
        const float c = rot_c(), sn = rot_s();
        float x0 = x[3*i], x1 = x[3*i+1], a = x[3*i+2];
        float u0 = rotate ? (c*x0 - sn*x1) : x0;
        float u1 = rotate ? (sn*x0 + c*x1) : x1;
        h0[i] = make_float4((u0 - mean0) * imx0, (u1 - mean1) * imx1, a * imxa, 0.f);
    }
    int idx = i;
    if (idx < 32768) {                       // Wpk2[ks8][nt8][lane64][j8], K=256,N=128
        int j = idx & 7, lane = (idx >> 3) & 63, nt = (idx >> 9) & 7, ks = idx >> 12;
        int k = ks*32 + (lane >> 4)*8 + j;
        int n = nt*16 + (lane & 15);
        float v = (k < 128) ? Wl2[n*H + k] : Wr2[n*H + (k - 128)];
        Wpk2[idx] = __float2bfloat16(v);
    } else if (idx < 65536) {                // Wpk1[ks4][nt16][lane64][j8], K=128,N=256
        int i2 = idx - 32768;
        int j = i2 & 7, lane = (i2 >> 3) & 63, nt = (i2 >> 9) & 15, ks = i2 >> 13;
        int k = ks*32 + (lane >> 4)*8 + j;
        int n = nt*16 + (lane & 15);
        Wpk1[i2] = __float2bfloat16(W1[n*H + k]);
    } else if (idx < 69632) {                // W2pk[ks8][lane64][j8], K=256,N=16(8 real)
        int i3 = idx - 65536;
        int j = i3 & 7, lane = (i3 >> 3) & 63, ks = i3 >> 9;
        int k = ks*32 + (lane >> 4)*8 + j;
        int n = lane & 15;
        W2pk[i3] = __float2bfloat16((n < CDIM) ? W2[n*LH + k] : 0.f);
    }
}

// ---------------- CSR build ----------------
__global__ void deg_count_k(const int* __restrict__ ei, int* __restrict__ deg) {
    int e = blockIdx.x * blockDim.x + threadIdx.x;
    if (e >= N_EDGES) return;
    atomicAdd(&deg[ei[N_EDGES + e]], 1);
}

__global__ void scan1_k(const int* __restrict__ deg, int* __restrict__ rowptr,
                        int* __restrict__ bsums) {
    __shared__ int s[256];
    int t = threadIdx.x;
    int base = blockIdx.x * 1024 + t * 4;
    int d0 = (base+0 < N_NODES) ? deg[base+0] : 0;
    int d1 = (base+1 < N_NODES) ? deg[base+1] : 0;
    int d2 = (base+2 < N_NODES) ? deg[base+2] : 0;
    int d3 = (base+3 < N_NODES) ? deg[base+3] : 0;
    int tsum = d0 + d1 + d2 + d3;
    s[t] = tsum;
    __syncthreads();
    for (int off = 1; off < 256; off <<= 1) {
        int v = (t >= off) ? s[t - off] : 0;
        __syncthreads();
        s[t] += v;
        __syncthreads();
    }
    int excl = s[t] - tsum;
    if (base+0 < N_NODES) rowptr[base+0] = excl;
    if (base+1 < N_NODES) rowptr[base+1] = excl + d0;
    if (base+2 < N_NODES) rowptr[base+2] = excl + d0 + d1;
    if (base+3 < N_NODES) rowptr[base+3] = excl + d0 + d1 + d2;
    if (t == 255) bsums[blockIdx.x] = s[255];
}

// scan3 with folded scan2: add = sum of bsums[0..blockIdx-1]
__global__ void scan3_k(int* __restrict__ rowptr, const int* __restrict__ bsums, int nb) {
    __shared__ int sb[256];
    int t = threadIdx.x;
    sb[t] = (t < (int)blockIdx.x && t < nb) ? bsums[t] : 0;
    __syncthreads();
    for (int s = 128; s > 0; s >>= 1) {
        if (t < s) sb[t] += sb[t + s];
        __syncthreads();
    }
    int add = sb[0];
    int base = blockIdx.x * 1024 + t * 4;
    if (base+0 < N_NODES) rowptr[base+0] += add;
    if (base+1 < N_NODES) rowptr[base+1] += add;
    if (base+2 < N_NODES) rowptr[base+2] += add;
    if (base+3 < N_NODES) rowptr[base+3] += add;
}

__global__ void scatter_k(const int* __restrict__ ei, int* __restrict__ rowptr,
                          int* __restrict__ csr) {
    int e = blockIdx.x * blockDim.x + threadIdx.x;
    if (e >= N_EDGES) return;
    int d = ei[N_EDGES + e];
    int pos = atomicAdd(&rowptr[d], 1);
    csr[pos] = ei[e];
}

// ---------------- fused agg1 + conv1 dense ----------------
__global__ __launch_bounds__(256) void agg1conv1_k(const float4* __restrict__ h0,
        const int* __restrict__ rowptr, const int* __restrict__ deg,
        const int* __restrict__ csr,
        const float* __restrict__ Wl1, const float* __restrict__ bl1,
        const float* __restrict__ Wr1, __hip_bfloat16* __restrict__ Xb) {
    __shared__ float wl[H*3], wr[H*3], bb[H];
    __shared__ float4 sa[256];
    int tid = threadIdx.x;
    for (int i = tid; i < H*3; i += 256) { wl[i] = Wl1[i]; wr[i] = Wr1[i]; }
    if (tid < H) bb[tid] = bl1[tid];
    int base = blockIdx.x * 256;
    int n = base + tid;
    float4 av = make_float4(0.f, 0.f, 0.f, 0.f);
    if (n < N_NODES) {
        int dg = deg[n];
        int end = rowptr[n], start = end - dg;
        float a0 = 0.f, a1 = 0.f, a2 = 0.f;
        int e = start;
        for (; e + 3 < end; e += 4) {
            int s0 = csr[e], s1 = csr[e+1], s2 = csr[e+2], s3 = csr[e+3];
            float4 v0 = h0[s0];
            float4 v1 = h0[s1];
            float4 v2 = h0[s2];
            float4 v3 = h0[s3];
            a0 += (v0.x + v1.x) + (v2.x + v3.x);
            a1 += (v0.y + v1.y) + (v2.y + v3.y);
            a2 += (v0.z + v1.z) + (v2.z + v3.z);
        }
        for (; e < end; e++) {
            float4 v = h0[csr[e]];
            a0 += v.x; a1 += v.y; a2 += v.z;
        }
        float inv = 1.0f / (float)max(dg, 1);
        av = make_float4(a0 * inv, a1 * inv, a2 * inv, 0.f);
    }
    sa[tid] = av;
    __syncthreads();
    int sub = tid >> 6;
    int j2 = (tid & 63) * 2;
    for (int i = 0; i < 64; i++) {
        int loc = i * 4 + sub;
        int nn = base + loc;
        if (nn >= N_NODES) break;
        float4 a = sa[loc];
        float4 xv = h0[nn];
        float o0 = wl[3*j2+0]*a.x + wl[3*j2+1]*a.y + wl[3*j2+2]*a.z + bb[j2]
                 + wr[3*j2+0]*xv.x + wr[3*j2+1]*xv.y + wr[3*j2+2]*xv.z;
        float o1 = wl[3*j2+3]*a.x + wl[3*j2+4]*a.y + wl[3*j2+5]*a.z + bb[j2+1]
                 + wr[3*j2+3]*xv.x + wr[3*j2+4]*xv.y + wr[3*j2+5]*xv.z;
        unsigned pv = ((unsigned)bfu(ftanh(o1)) << 16) | (unsigned)bfu(ftanh(o0));
        *(unsigned*)&Xb[(size_t)nn*256 + 128 + j2] = pv;
    }
}

// ---------------- FUSED agg2 + conv2 + MLP + softmax ----------------
// Per 128-row tile, per wave (16 rows, wave-private throughout, NO barriers):
//   phase A: gather agg2 means (16 lanes/node, uint4 = 256B coalesced row
//            reads, fp32 acc, bf16 round) -> own Cs slice (XOR swizzle)
//   conv2:   A-frags ks0..3 from Cs slice, ks4..7 = own-row h1 (prefetched);
//            h2 = tanh(.) -> same slice
//   GEMM1:   slice as A-frags x W1 -> t; GEMM2 chunked via slice vs W2 regs
//   softmax via 8-lane shuffle. agg2/h2 NEVER touch HBM.
// LDS: Ws2 64K + Ws1 64K + Cs 32K = 160 KB -> 1 block/CU, 8 waves, 2/SIMD.
__global__ __launch_bounds__(512, 1) void conv2mlp_k(const __hip_bfloat16* __restrict__ Xb,
        const int* __restrict__ rowptr, const int* __restrict__ deg,
        const int* __restrict__ csr,
        const __hip_bfloat16* __restrict__ Wpk2, const float* __restrict__ bl2,
        const __hip_bfloat16* __restrict__ Wpk1, const float* __restrict__ b1,
        const __hip_bfloat16* __restrict__ W2pk, const float* __restrict__ b2,
        float* __restrict__ out) {
    __shared__ short Ws2[32768];         // conv2 weights [ks8][nt8][lane64][j8]
    __shared__ short Ws1[32768];         // W1 weights [ks4][nt16][lane64][j8]
    __shared__ short Cs[8 * 16 * 128];   // per-wave 16x128 swizzled staging
    int tid = threadIdx.x;
    int lane = tid & 63, wave = tid >> 6;
    int quad = lane >> 4, m = lane & 15, c0 = lane & 15;
    {
        // 512 threads x 8 iters x 16 B = exactly 64 KB per array
        const float4* s2 = (const float4*)Wpk2;
        const float4* s1 = (const float4*)Wpk1;
        float4* d2 = (float4*)Ws2;
        float4* d1 = (float4*)Ws1;
        #pragma unroll
        for (int i = 0; i < 8; i++) {
            d2[tid + i*512] = s2[tid + i*512];
            d1[tid + i*512] = s1[tid + i*512];
        }
    }
    // W2 fragments + biases -> registers (persistent)
    short8 w2f[8];
    #pragma unroll
    for (int ks = 0; ks < 8; ks++)
        w2f[ks] = *(const short8*)&W2pk[(ks*64 + lane)*8];
    float bl2r[8], b1r[16];
    #pragma unroll
    for (int nt = 0; nt < 8; nt++) bl2r[nt] = bl2[nt*16 + c0];
    #pragma unroll
    for (int nt = 0; nt < 16; nt++) b1r[nt] = b1[nt*16 + c0];
    float b2v = (c0 < CDIM) ? b2[c0] : 0.f;
    __syncthreads();
    short* Tw = &Cs[wave * (16 * 128)];
    const short* XbS = (const short*)Xb;
    int grp = lane >> 4;     // 4 node-groups of 16 lanes per wave
    int l16 = lane & 15;     // covers cols l16*8..+7 (one 16B granule)

    int tile = blockIdx.x;
    short8 hreg[4];          // own-row h1 A-frags (ks 4..7)
    {
        int row = tile*128 + wave*16 + m;
        int rowL = row < N_NODES ? row : N_NODES - 1;
        const short* Arow = XbS + (size_t)rowL * 256;
        #pragma unroll
        for (int j = 0; j < 4; j++)
            hreg[j] = *(const short8*)(Arow + 128 + j*32 + quad*8);
    }
    for (; tile < NT128; tile += gridDim.x) {
        // ---- phase A: agg2 gather into own Cs slice (wave-private)
        #pragma unroll
        for (int i = 0; i < 4; i++) {
            int r = grp*4 + i;                      // row within slice
            int node = tile*128 + wave*16 + r;
            int nodeL = node < N_NODES ? node : N_NODES - 1;
            int dg = deg[nodeL];
            int end = rowptr[nodeL];
            int e = end - dg;
            float a0=0.f,a1=0.f,a2=0.f,a3=0.f,a4=0.f,a5=0.f,a6=0.f,a7=0.f;
            for (; e + 1 < end; e += 2) {
                int s0 = csr[e], s1 = csr[e+1];
                uint4 v0 = *(const uint4*)&XbS[(size_t)s0*256 + 128 + l16*8];
                uint4 v1 = *(const uint4*)&XbS[(size_t)s1*256 + 128 + l16*8];
                a0 += bflo(v0.x) + bflo(v1.x); a1 += bfhi(v0.x) + bfhi(v1.x);
                a2 += bflo(v0.y) + bflo(v1.y); a3 += bfhi(v0.y) + bfhi(v1.y);
                a4 += bflo(v0.z) + bflo(v1.z); a5 += bfhi(v0.z) + bfhi(v1.z);
                a6 += bflo(v0.w) + bflo(v1.w); a7 += bfhi(v0.w) + bfhi(v1.w);
            }
            if (e < end) {
                int s0 = csr[e];
                uint4 v0 = *(const uint4*)&XbS[(size_t)s0*256 + 128 + l16*8];
                a0 += bflo(v0.x); a1 += bfhi(v0.x);
                a2 += bflo(v0.y); a3 += bfhi(v0.y);
                a4 += bflo(v0.z); a5 += bfhi(v0.z);
                a6 += bflo(v0.w); a7 += bfhi(v0.w);
            }
            float inv = 1.0f / (float)max(dg, 1);
            uint4 o;
            o.x = ((unsigned)bfu(a1*inv) << 16) | (unsigned)bfu(a0*inv);
            o.y = ((unsigned)bfu(a3*inv) << 16) | (unsigned)bfu(a2*inv);
            o.z = ((unsigned)bfu(a5*inv) << 16) | (unsigned)bfu(a4*inv);
            o.w = ((unsigned)bfu(a7*inv) << 16) | (unsigned)bfu(a6*inv);
            *(uint4*)&Tw[r*128 + ((l16 ^ r) << 3)] = o;   // swizzled 16B store
        }
        // prefetch next tile's h1 A-frags
        short8 hnext[4];
        {
            int tnext = tile + gridDim.x;
            int rown = (tnext < NT128) ? (tnext*128 + wave*16 + m) : 0;
            int rowNL = rown < N_NODES ? rown : N_NODES - 1;
            const short* ArowN = XbS + (size_t)rowNL * 256;
            #pragma unroll
            for (int j = 0; j < 4; j++)
                hnext[j] = *(const short8*)(ArowN + 128 + j*32 + quad*8);
        }
        // ---- conv2: h2 = tanh([agg2|h1] @ W' + bl2)
        floatx4 acc2[8];
        #pragma unroll
        for (int i = 0; i < 8; i++)
            #pragma unroll
            for (int r = 0; r < 4; r++) acc2[i][r] = 0.f;
        #pragma unroll
        for (int ks = 0; ks < 8; ks++) {
            short8 a;
            if (ks < 4)
                a = *(const short8*)&Tw[m*128 + (((ks*4 + quad) ^ m) << 3)];
            else
                a = hreg[ks - 4];
            #pragma unroll
            for (int nt = 0; nt < 8; nt++) {
                short8 b = *(const short8*)&Ws2[((ks*8 + nt)*64 + lane)*8];
                acc2[nt] = __builtin_amdgcn_mfma_f32_16x16x32_bf16(a, b, acc2[nt], 0, 0, 0);
            }
        }
        #pragma unroll
        for (int nt = 0; nt < 8; nt++) {
            int cg = nt*2 + (c0 >> 3);
            #pragma unroll
            for (int r = 0; r < 4; r++) {
                int row = quad*4 + r;
                Tw[row*128 + ((cg ^ row) << 3) + (c0 & 7)] =
                    (short)bfu(ftanh(acc2[nt][r] + bl2r[nt]));
            }
        }
        // ---- GEMM1: t_pre = h2 @ W1^T  (A from the slice just written)
        floatx4 acc1[16];
        #pragma unroll
        for (int i = 0; i < 16; i++)
            #pragma unroll
            for (int r = 0; r < 4; r++) acc1[i][r] = 0.f;
        #pragma unroll
        for (int ks = 0; ks < 4; ks++) {
            short8 a = *(const short8*)&Tw[m*128 + (((ks*4 + quad) ^ m) << 3)];
            #pragma unroll
            for (int nt = 0; nt < 16; nt++) {
                short8 b = *(const short8*)&Ws1[((ks*16 + nt)*64 + lane)*8];
                acc1[nt] = __builtin_amdgcn_mfma_f32_16x16x32_bf16(a, b, acc1[nt], 0, 0, 0);
            }
        }
        // ---- GEMM2 in 4 K-chunks through the (now dead) slice
        floatx4 lacc;
        #pragma unroll
        for (int r = 0; r < 4; r++) lacc[r] = 0.f;
        #pragma unroll
        for (int ch = 0; ch < 4; ch++) {
            #pragma unroll
            for (int ntl = 0; ntl < 4; ntl++) {
                int nt = ch*4 + ntl;
                int cg = ntl*2 + (c0 >> 3);
                #pragma unroll
                for (int r = 0; r < 4; r++) {
                    int row = quad*4 + r;
                    Tw[row*128 + ((cg ^ row) << 3) + (c0 & 7)] =
                        (short)bfu(ftanh(acc1[nt][r] + b1r[nt]));
                }
            }
            #pragma unroll
            for (int k2 = 0; k2 < 2; k2++) {
                short8 a = *(const short8*)&Tw[m*128 + (((k2*4 + quad) ^ m) << 3)];
                lacc = __builtin_amdgcn_mfma_f32_16x16x32_bf16(a, w2f[ch*2 + k2], lacc, 0, 0, 0);
            }
        }
        // ---- softmax across the 8 class lanes
        int rbase = tile*128 + wave*16 + quad*4;
        #pragma unroll
        for (int r = 0; r < 4; r++) {
            float v = lacc[r] + b2v;
            float mval = (c0 < CDIM) ? v : -INFINITY;
            #pragma unroll
            for (int off = 1; off < 8; off <<= 1)
                mval = fmaxf(mval, __shfl_xor(mval, off));
            float e = (c0 < CDIM) ? __expf(v - mval) : 0.f;
            float ssum = e;
            #pragma unroll
            for (int off = 1; off < 8; off <<= 1)
                ssum += __shfl_xor(ssum, off);
            int rowg = rbase + r;
            if (c0 < CDIM && rowg < N_NODES)
                out[(size_t)rowg*CDIM + c0] = e / ssum;
        }
        #pragma unroll
        for (int j = 0; j < 4; j++) hreg[j] = hnext[j];
    }
}

extern "C" void kernel_launch(void* const* d_in, const int* in_sizes, int n_in,
                              void* d_out, int out_size, void* d_ws, size_t ws_size,
                              hipStream_t stream) {
    const float* x   = (const float*)d_in[0];
    const int*   ei  = (const int*)d_in[1];
    const float* Wl1 = (const float*)d_in[2];
    const float* bl1 = (const float*)d_in[3];
    const float* Wr1 = (const float*)d_in[4];
    const float* Wl2 = (const float*)d_in[5];
    const float* bl2 = (const float*)d_in[6];
    const float* Wr2 = (const float*)d_in[7];
    const float* W1  = (const float*)d_in[8];
    const float* b1  = (const float*)d_in[9];
    const float* W2  = (const float*)d_in[10];
    const float* b2  = (const float*)d_in[11];

    float* ws     = (float*)d_ws;
    float* part   = ws + OFF_PART;
    int*   deg    = (int*)(ws + OFF_DEG);
    int*   rowptr = (int*)(ws + OFF_ROWPTR);
    int*   bsums  = (int*)(ws + OFF_BSUMS);
    float4* h0    = (float4*)(ws + OFF_H0);
    int*   csr    = (int*)(ws + OFF_CSR);
    __hip_bfloat16* Wpk2 = (__hip_bfloat16*)(ws + OFF_WPK2);
    __hip_bfloat16* Wpk1 = (__hip_bfloat16*)(ws + OFF_WPK1);
    __hip_bfloat16* W2pk = (__hip_bfloat16*)(ws + OFF_W2PK);
    __hip_bfloat16* Xb   = (__hip_bfloat16*)(ws + OFF_XB);

    const int nb_scan = (N_NODES + 1023) / 1024;   // 98

    stats_partial_k<<<NB_STATS, 256, 0, stream>>>(x, part, deg);
    normalize_k<<<(N_NODES + 255) / 256, 256, 0, stream>>>(x, part, h0,
            Wl2, Wr2, W1, W2, Wpk2, Wpk1, W2pk);
    deg_count_k<<<(N_EDGES + 255) / 256, 256, 0, stream>>>(ei, deg);
    scan1_k<<<nb_scan, 256, 0, stream>>>(deg, rowptr, bsums);
    scan3_k<<<nb_scan, 256, 0, stream>>>(rowptr, bsums, nb_scan);
    scatter_k<<<(N_EDGES + 255) / 256, 256, 0, stream>>>(ei, rowptr, csr);

    agg1conv1_k<<<(N_NODES + 255) / 256, 256, 0, stream>>>(h0, rowptr, deg, csr,
            Wl1, bl1, Wr1, Xb);
    conv2mlp_k<<<256, 512, 0, stream>>>(Xb, rowptr, deg, csr,
            Wpk2, bl2, Wpk1, b1, W2pk, b2, (float*)d_out);
}

// Round 13
// 267.355 us; speedup vs baseline: 1.0757x; 1.0757x over previous
//
#include <hip/hip_runtime.h>
#include <hip/hip_bf16.h>
#include <math.h>

#define N_NODES 100000
#define N_EDGES 600000
#define H 128
#define LH 256
#define CDIM 8
#define NB_STATS 64
#define NT128 ((N_NODES + 127) / 128)   // 782 (128-row tiles, fused kernel)

typedef __attribute__((ext_vector_type(8))) short short8;
typedef __attribute__((ext_vector_type(4))) float floatx4;

// ------------- workspace layout (4-byte words) -------------
#define OFF_PART   0
#define OFF_PARAMS 704
#define OFF_DEG    712
#define OFF_ROWPTR (OFF_DEG + N_NODES)
#define OFF_BSUMS  (OFF_ROWPTR + N_NODES)
#define OFF_H0     (OFF_BSUMS + 128)            // N*4 fp32 (float4 rows)
#define OFF_AGG1   (OFF_H0 + N_NODES*4)         // (unused, kept for layout)
#define OFF_CSR    (OFF_AGG1 + N_NODES*4)
#define OFF_WPK2   (OFF_CSR + N_EDGES)          // 32768 bf16 = 16384 words
#define OFF_WPK1   (OFF_WPK2 + 16384)           // 32768 bf16
#define OFF_W2PK   (OFF_WPK1 + 16384)           // 4096 bf16 = 2048 words
#define OFF_XB     (OFF_W2PK + 2048)            // N*256 bf16 = 12.8M words

__device__ __forceinline__ float rot_c() { return cosf(1.57079632679489661923f); }
__device__ __forceinline__ float rot_s() { return sinf(1.57079632679489661923f); }
__device__ __forceinline__ float bfhi(unsigned v) { return __uint_as_float(v & 0xffff0000u); }
__device__ __forceinline__ float bflo(unsigned v) { return __uint_as_float(v << 16); }
__device__ __forceinline__ unsigned short bfu(float f) {
    __hip_bfloat16 h = __float2bfloat16(f);
    return *(unsigned short*)&h;
}
// fast tanh: 1 - 2/(e^{2x}+1). Exact at +-inf (rcp(inf)=0), rel err ~1e-6,
// far below bf16 quantization (~4e-3). ~5 VALU ops vs ~40 for libm tanhf.
__device__ __forceinline__ float ftanh(float x) {
    float e = __expf(2.0f * x);
    return 1.0f - 2.0f * __builtin_amdgcn_rcpf(e + 1.0f);
}

// ---------------- stats partial (also zeroes deg) ----------------
__global__ void stats_partial_k(const float* __restrict__ x, float* __restrict__ part,
                                int* __restrict__ deg) {
    const float c = rot_c(), sn = rot_s();
    float mn0 = INFINITY, mx0 = -INFINITY, mn1 = INFINITY, mx1 = -INFINITY;
    float s0 = 0.f, s1 = 0.f, sr0 = 0.f, sr1 = 0.f;
    float mxr0 = -INFINITY, mxr1 = -INFINITY, mxa = -INFINITY;
    for (int i = blockIdx.x * blockDim.x + threadIdx.x; i < N_NODES;
         i += gridDim.x * blockDim.x) {
        deg[i] = 0;
        float x0 = x[3*i], x1 = x[3*i+1], a = x[3*i+2];
        float r0 = c*x0 - sn*x1;
        float r1 = sn*x0 + c*x1;
        mn0 = fminf(mn0, x0); mx0 = fmaxf(mx0, x0);
        mn1 = fminf(mn1, x1); mx1 = fmaxf(mx1, x1);
        s0 += x0; s1 += x1; sr0 += r0; sr1 += r1;
        mxr0 = fmaxf(mxr0, r0); mxr1 = fmaxf(mxr1, r1);
        mxa = fmaxf(mxa, a);
    }
    __shared__ float red[256];
    float vals[11] = {mn0, mx0, mn1, mx1, s0, s1, sr0, sr1, mxr0, mxr1, mxa};
    const int ops[11] = {0,1,0,1,2,2,2,2,1,1,1};
    for (int v = 0; v < 11; v++) {
        red[threadIdx.x] = vals[v];
        __syncthreads();
        for (int s = 128; s > 0; s >>= 1) {
            if ((int)threadIdx.x < s) {
                float a = red[threadIdx.x], b = red[threadIdx.x + s];
                red[threadIdx.x] = (ops[v]==0) ? fminf(a,b) : (ops[v]==1) ? fmaxf(a,b) : (a+b);
            }
            __syncthreads();
        }
        if (threadIdx.x == 0) part[blockIdx.x * 11 + v] = red[0];
        __syncthreads();
    }
}

// ---------------- normalize (+ final stats reduce + pre-pack + deg_count) --
// deg was fully zeroed by stats_partial_k (completes before this launches).
__global__ __launch_bounds__(256) void normalize_k(const float* __restrict__ x,
        const float* __restrict__ part, float4* __restrict__ h0,
        const float* __restrict__ Wl2, const float* __restrict__ Wr2,
        const float* __restrict__ W1, const float* __restrict__ W2,
        __hip_bfloat16* __restrict__ Wpk2, __hip_bfloat16* __restrict__ Wpk1,
        __hip_bfloat16* __restrict__ W2pk,
        const int* __restrict__ ei, int* __restrict__ deg) {
    __shared__ float res[11];
    int tid = threadIdx.x;
    if (tid < 64) {
        const int ops[11] = {0,1,0,1,2,2,2,2,1,1,1};
        for (int v = 0; v < 11; v++) {
            float val = part[tid * 11 + v];
            #pragma unroll
            for (int off = 32; off > 0; off >>= 1) {
                float o = __shfl_down(val, off);
                val = (ops[v]==0) ? fminf(val,o) : (ops[v]==1) ? fmaxf(val,o) : (val+o);
            }
            if (tid == 0) res[v] = val;
        }
    }
    __syncthreads();
    int rotate = (res[3] - res[2]) > (res[1] - res[0]);
    float mean0 = (rotate ? res[6] : res[4]) / (float)N_NODES;
    float mean1 = (rotate ? res[7] : res[5]) / (float)N_NODES;
    float imx0  = 1.0f / (rotate ? res[8] : res[1]);
    float imx1  = 1.0f / (rotate ? res[9] : res[3]);
    float imxa  = 1.0f / res[10];

    int i = blockIdx.x * blockDim.x + tid;
    if (i < N_NODES) {
        const float c = rot_c(), sn = rot_s();
        float x0 = x[3*i], x1 = x[3*i+1], a = x[3*i+2];
        float u0 = rotate ? (c*x0 - sn*x1) : x0;
        float u1 = rotate ? (sn*x0 + c*x1) : x1;
        h0[i] = make_float4((u0 - mean0) * imx0, (u1 - mean1) * imx1, a * imxa, 0.f);
    }
    int idx = i;
    if (idx < 32768) {                       // Wpk2[ks8][nt8][lane64][j8], K=256,N=128
        int j = idx & 7, lane = (idx >> 3) & 63, nt = (idx >> 9) & 7, ks = idx >> 12;
        int k = ks*32 + (lane >> 4)*8 + j;
        int n = nt*16 + (lane & 15);
        float v = (k < 128) ? Wl2[n*H + k] : Wr2[n*H + (k - 128)];
        Wpk2[idx] = __float2bfloat16(v);
    } else if (idx < 65536) {                // Wpk1[ks4][nt16][lane64][j8], K=128,N=256
        int i2 = idx - 32768;
        int j = i2 & 7, lane = (i2 >> 3) & 63, nt = (i2 >> 9) & 15, ks = i2 >> 13;
        int k = ks*32 + (lane >> 4)*8 + j;
        int n = nt*16 + (lane & 15);
        Wpk1[i2] = __float2bfloat16(W1[n*H + k]);
    } else if (idx < 69632) {                // W2pk[ks8][lane64][j8], K=256,N=16(8 real)
        int i3 = idx - 65536;
        int j = i3 & 7, lane = (i3 >> 3) & 63, ks = i3 >> 9;
        int k = ks*32 + (lane >> 4)*8 + j;
        int n = lane & 15;
        W2pk[i3] = __float2bfloat16((n < CDIM) ? W2[n*LH + k] : 0.f);
    }
    // folded deg_count: grid-stride over edges (~6 atomics/thread)
    int nthreads = gridDim.x * blockDim.x;
    for (int e = i; e < N_EDGES; e += nthreads)
        atomicAdd(&deg[ei[N_EDGES + e]], 1);
}

// ---------------- CSR build ----------------
__global__ void scan1_k(const int* __restrict__ deg, int* __restrict__ rowptr,
                        int* __restrict__ bsums) {
    __shared__ int s[256];
    int t = threadIdx.x;
    int base = blockIdx.x * 1024 + t * 4;
    int d0 = (base+0 < N_NODES) ? deg[base+0] : 0;
    int d1 = (base+1 < N_NODES) ? deg[base+1] : 0;
    int d2 = (base+2 < N_NODES) ? deg[base+2] : 0;
    int d3 = (base+3 < N_NODES) ? deg[base+3] : 0;
    int tsum = d0 + d1 + d2 + d3;
    s[t] = tsum;
    __syncthreads();
    for (int off = 1; off < 256; off <<= 1) {
        int v = (t >= off) ? s[t - off] : 0;
        __syncthreads();
        s[t] += v;
        __syncthreads();
    }
    int excl = s[t] - tsum;
    if (base+0 < N_NODES) rowptr[base+0] = excl;
    if (base+1 < N_NODES) rowptr[base+1] = excl + d0;
    if (base+2 < N_NODES) rowptr[base+2] = excl + d0 + d1;
    if (base+3 < N_NODES) rowptr[base+3] = excl + d0 + d1 + d2;
    if (t == 255) bsums[blockIdx.x] = s[255];
}

// scan3 with folded scan2: add = sum of bsums[0..blockIdx-1]
__global__ void scan3_k(int* __restrict__ rowptr, const int* __restrict__ bsums, int nb) {
    __shared__ int sb[256];
    int t = threadIdx.x;
    sb[t] = (t < (int)blockIdx.x && t < nb) ? bsums[t] : 0;
    __syncthreads();
    for (int s = 128; s > 0; s >>= 1) {
        if (t < s) sb[t] += sb[t + s];
        __syncthreads();
    }
    int add = sb[0];
    int base = blockIdx.x * 1024 + t * 4;
    if (base+0 < N_NODES) rowptr[base+0] += add;
    if (base+1 < N_NODES) rowptr[base+1] += add;
    if (base+2 < N_NODES) rowptr[base+2] += add;
    if (base+3 < N_NODES) rowptr[base+3] += add;
}

__global__ void scatter_k(const int* __restrict__ ei, int* __restrict__ rowptr,
                          int* __restrict__ csr) {
    int e = blockIdx.x * blockDim.x + threadIdx.x;
    if (e >= N_EDGES) return;
    int d = ei[N_EDGES + e];
    int pos = atomicAdd(&rowptr[d], 1);
    csr[pos] = ei[e];
}

// ---------------- fused agg1 + conv1 dense ----------------
__global__ __launch_bounds__(256) void agg1conv1_k(const float4* __restrict__ h0,
        const int* __restrict__ rowptr, const int* __restrict__ deg,
        const int* __restrict__ csr,
        const float* __restrict__ Wl1, const float* __restrict__ bl1,
        const float* __restrict__ Wr1, __hip_bfloat16* __restrict__ Xb) {
    __shared__ float wl[H*3], wr[H*3], bb[H];
    __shared__ float4 sa[256];
    int tid = threadIdx.x;
    for (int i = tid; i < H*3; i += 256) { wl[i] = Wl1[i]; wr[i] = Wr1[i]; }
    if (tid < H) bb[tid] = bl1[tid];
    int base = blockIdx.x * 256;
    int n = base + tid;
    float4 av = make_float4(0.f, 0.f, 0.f, 0.f);
    if (n < N_NODES) {
        int dg = deg[n];
        int end = rowptr[n], start = end - dg;
        float a0 = 0.f, a1 = 0.f, a2 = 0.f;
        int e = start;
        for (; e + 3 < end; e += 4) {
            int s0 = csr[e], s1 = csr[e+1], s2 = csr[e+2], s3 = csr[e+3];
            float4 v0 = h0[s0];
            float4 v1 = h0[s1];
            float4 v2 = h0[s2];
            float4 v3 = h0[s3];
            a0 += (v0.x + v1.x) + (v2.x + v3.x);
            a1 += (v0.y + v1.y) + (v2.y + v3.y);
            a2 += (v0.z + v1.z) + (v2.z + v3.z);
        }
        for (; e < end; e++) {
            float4 v = h0[csr[e]];
            a0 += v.x; a1 += v.y; a2 += v.z;
        }
        float inv = 1.0f / (float)max(dg, 1);
        av = make_float4(a0 * inv, a1 * inv, a2 * inv, 0.f);
    }
    sa[tid] = av;
    __syncthreads();
    int sub = tid >> 6;
    int j2 = (tid & 63) * 2;
    for (int i = 0; i < 64; i++) {
        int loc = i * 4 + sub;
        int nn = base + loc;
        if (nn >= N_NODES) break;
        float4 a = sa[loc];
        float4 xv = h0[nn];
        float o0 = wl[3*j2+0]*a.x + wl[3*j2+1]*a.y + wl[3*j2+2]*a.z + bb[j2]
                 + wr[3*j2+0]*xv.x + wr[3*j2+1]*xv.y + wr[3*j2+2]*xv.z;
        float o1 = wl[3*j2+3]*a.x + wl[3*j2+4]*a.y + wl[3*j2+5]*a.z + bb[j2+1]
                 + wr[3*j2+3]*xv.x + wr[3*j2+4]*xv.y + wr[3*j2+5]*xv.z;
        unsigned pv = ((unsigned)bfu(ftanh(o1)) << 16) | (unsigned)bfu(ftanh(o0));
        *(unsigned*)&Xb[(size_t)nn*256 + 128 + j2] = pv;
    }
}

// ---------------- agg2: mean of h1 (bf16) -> Xb[n][0..127]
// half-wave (32 lanes) per node, 4 cols/lane: 32*4 = exactly 128 cols.
__global__ void agg2_k(__hip_bfloat16* __restrict__ Xb, const int* __restrict__ rowptr,
                       const int* __restrict__ deg, const int* __restrict__ csr) {
    int lane = threadIdx.x & 31;
    int n = blockIdx.x * 8 + (threadIdx.x >> 5);
    int dg = deg[n];
    int end = rowptr[n], start = end - dg;
    float a0 = 0.f, a1 = 0.f, a2 = 0.f, a3 = 0.f;
    int e = start;
    for (; e + 3 < end; e += 4) {
        int s0 = csr[e], s1 = csr[e+1], s2 = csr[e+2], s3 = csr[e+3];
        uint2 v0 = *(const uint2*)&Xb[(size_t)s0*256 + 128 + lane*4];
        uint2 v1 = *(const uint2*)&Xb[(size_t)s1*256 + 128 + lane*4];
        uint2 v2 = *(const uint2*)&Xb[(size_t)s2*256 + 128 + lane*4];
        uint2 v3 = *(const uint2*)&Xb[(size_t)s3*256 + 128 + lane*4];
        a0 += (bflo(v0.x) + bflo(v1.x)) + (bflo(v2.x) + bflo(v3.x));
        a1 += (bfhi(v0.x) + bfhi(v1.x)) + (bfhi(v2.x) + bfhi(v3.x));
        a2 += (bflo(v0.y) + bflo(v1.y)) + (bflo(v2.y) + bflo(v3.y));
        a3 += (bfhi(v0.y) + bfhi(v1.y)) + (bfhi(v2.y) + bfhi(v3.y));
    }
    for (; e < end; e++) {
        uint2 v = *(const uint2*)&Xb[(size_t)csr[e]*256 + 128 + lane*4];
        a0 += bflo(v.x); a1 += bfhi(v.x); a2 += bflo(v.y); a3 += bfhi(v.y);
    }
    float inv = 1.0f / (float)max(dg, 1);
    uint2 o;
    o.x = ((unsigned)bfu(a1*inv) << 16) | (unsigned)bfu(a0*inv);
    o.y = ((unsigned)bfu(a3*inv) << 16) | (unsigned)bfu(a2*inv);
    *(uint2*)&Xb[(size_t)n*256 + lane*4] = o;
}

// ---------------- FUSED conv2 + MLP + softmax (8 waves, 2/SIMD) ----------
// 512 threads share Ws2+Ws1 (128 KB); per-wave 16x128 staging slice with XOR
// swizzle (group' = group ^ row at 16B granularity) -> no padding, 32 KB.
// Total LDS = 160 KB = 1 block/CU = 8 waves/CU = 2 waves/SIMD.
// Cs index (shorts): row*128 + ((colgrp ^ row)<<3) + (col&7), colgrp = col>>3.
__global__ __launch_bounds__(512, 1) void conv2mlp_k(const __hip_bfloat16* __restrict__ Xb,
        const __hip_bfloat16* __restrict__ Wpk2, const float* __restrict__ bl2,
        const __hip_bfloat16* __restrict__ Wpk1, const float* __restrict__ b1,
        const __hip_bfloat16* __restrict__ W2pk, const float* __restrict__ b2,
        float* __restrict__ out) {
    __shared__ short Ws2[32768];         // conv2 weights [ks8][nt8][lane64][j8]
    __shared__ short Ws1[32768];         // W1 weights [ks4][nt16][lane64][j8]
    __shared__ short Cs[8 * 16 * 128];   // per-wave 16x128 swizzled staging
    int tid = threadIdx.x;
    int lane = tid & 63, wave = tid >> 6;
    int quad = lane >> 4, m = lane & 15, c0 = lane & 15;
    {
        // 512 threads x 8 iters x 16 B = exactly 64 KB per array
        const float4* s2 = (const float4*)Wpk2;
        const float4* s1 = (const float4*)Wpk1;
        float4* d2 = (float4*)Ws2;
        float4* d1 = (float4*)Ws1;
        #pragma unroll
        for (int i = 0; i < 8; i++) {
            d2[tid + i*512] = s2[tid + i*512];
            d1[tid + i*512] = s1[tid + i*512];
        }
    }
    // W2 fragments + biases -> registers (persistent)
    short8 w2f[8];
    #pragma unroll
    for (int ks = 0; ks < 8; ks++)
        w2f[ks] = *(const short8*)&W2pk[(ks*64 + lane)*8];
    float bl2r[8], b1r[16];
    #pragma unroll
    for (int nt = 0; nt < 8; nt++) bl2r[nt] = bl2[nt*16 + c0];
    #pragma unroll
    for (int nt = 0; nt < 16; nt++) b1r[nt] = b1[nt*16 + c0];
    float b2v = (c0 < CDIM) ? b2[c0] : 0.f;
    __syncthreads();
    short* Tw = &Cs[wave * (16 * 128)];

    int tile = blockIdx.x;
    short8 areg[8];
    {
        int row = tile*128 + wave*16 + m;
        int rowL = row < N_NODES ? row : N_NODES - 1;
        const short* Arow = (const short*)Xb + (size_t)rowL * 256;
        #pragma unroll
        for (int ks = 0; ks < 8; ks++)
            areg[ks] = *(const short8*)(Arow + ks*32 + quad*8);
    }
    for (; tile < NT128; tile += gridDim.x) {
        // prefetch next tile's A fragments
        short8 anext[8];
        {
            int tnext = tile + gridDim.x;
            int rown = (tnext < NT128) ? (tnext*128 + wave*16 + m) : 0;
            int rowNL = rown < N_NODES ? rown : N_NODES - 1;
            const short* ArowN = (const short*)Xb + (size_t)rowNL * 256;
            #pragma unroll
            for (int ks = 0; ks < 8; ks++)
                anext[ks] = *(const short8*)(ArowN + ks*32 + quad*8);
        }
        // ---- conv2: h2 = tanh([agg2|h1] @ W' + bl2)
        floatx4 acc2[8];
        #pragma unroll
        for (int i = 0; i < 8; i++)
            #pragma unroll
            for (int r = 0; r < 4; r++) acc2[i][r] = 0.f;
        #pragma unroll
        for (int ks = 0; ks < 8; ks++) {
            #pragma unroll
            for (int nt = 0; nt < 8; nt++) {
                short8 b = *(const short8*)&Ws2[((ks*8 + nt)*64 + lane)*8];
                acc2[nt] = __builtin_amdgcn_mfma_f32_16x16x32_bf16(areg[ks], b, acc2[nt], 0, 0, 0);
            }
        }
        #pragma unroll
        for (int nt = 0; nt < 8; nt++) {
            int cg = nt*2 + (c0 >> 3);
            #pragma unroll
            for (int r = 0; r < 4; r++) {
                int row = quad*4 + r;
                Tw[row*128 + ((cg ^ row) << 3) + (c0 & 7)] =
                    (short)bfu(ftanh(acc2[nt][r] + bl2r[nt]));
            }
        }
        // ---- GEMM1: t_pre = h2 @ W1^T  (A from the slice just written)
        floatx4 acc1[16];
        #pragma unroll
        for (int i = 0; i < 16; i++)
            #pragma unroll
            for (int r = 0; r < 4; r++) acc1[i][r] = 0.f;
        #pragma unroll
        for (int ks = 0; ks < 4; ks++) {
            short8 a = *(const short8*)&Tw[m*128 + (((ks*4 + quad) ^ m) << 3)];
            #pragma unroll
            for (int nt = 0; nt < 16; nt++) {
                short8 b = *(const short8*)&Ws1[((ks*16 + nt)*64 + lane)*8];
                acc1[nt] = __builtin_amdgcn_mfma_f32_16x16x32_bf16(a, b, acc1[nt], 0, 0, 0);
            }
        }
        // ---- GEMM2 in 4 K-chunks through the (now dead) slice
        floatx4 lacc;
        #pragma unroll
        for (int r = 0; r < 4; r++) lacc[r] = 0.f;
        #pragma unroll
        for (int ch = 0; ch < 4; ch++) {
            #pragma unroll
            for (int ntl = 0; ntl < 4; ntl++) {
                int nt = ch*4 + ntl;
                int cg = ntl*2 + (c0 >> 3);
                #pragma unroll
                for (int r = 0; r < 4; r++) {
                    int row = quad*4 + r;
                    Tw[row*128 + ((cg ^ row) << 3) + (c0 & 7)] =
                        (short)bfu(ftanh(acc1[nt][r] + b1r[nt]));
                }
            }
            #pragma unroll
            for (int k2 = 0; k2 < 2; k2++) {
                short8 a = *(const short8*)&Tw[m*128 + (((k2*4 + quad) ^ m) << 3)];
                lacc = __builtin_amdgcn_mfma_f32_16x16x32_bf16(a, w2f[ch*2 + k2], lacc, 0, 0, 0);
            }
        }
        // ---- softmax across the 8 class lanes
        int rbase = tile*128 + wave*16 + quad*4;
        #pragma unroll
        for (int r = 0; r < 4; r++) {
            float v = lacc[r] + b2v;
            float mval = (c0 < CDIM) ? v : -INFINITY;
            #pragma unroll
            for (int off = 1; off < 8; off <<= 1)
                mval = fmaxf(mval, __shfl_xor(mval, off));
            float e = (c0 < CDIM) ? __expf(v - mval) : 0.f;
            float ssum = e;
            #pragma unroll
            for (int off = 1; off < 8; off <<= 1)
                ssum += __shfl_xor(ssum, off);
            int rowg = rbase + r;
            if (c0 < CDIM && rowg < N_NODES)
                out[(size_t)rowg*CDIM + c0] = e / ssum;
        }
        #pragma unroll
        for (int ks = 0; ks < 8; ks++) areg[ks] = anext[ks];
    }
}

extern "C" void kernel_launch(void* const* d_in, const int* in_sizes, int n_in,
                              void* d_out, int out_size, void* d_ws, size_t ws_size,
                              hipStream_t stream) {
    const float* x   = (const float*)d_in[0];
    const int*   ei  = (const int*)d_in[1];
    const float* Wl1 = (const float*)d_in[2];
    const float* bl1 = (const float*)d_in[3];
    const float* Wr1 = (const float*)d_in[4];
    const float* Wl2 = (const float*)d_in[5];
    const float* bl2 = (const float*)d_in[6];
    const float* Wr2 = (const float*)d_in[7];
    const float* W1  = (const float*)d_in[8];
    const float* b1  = (const float*)d_in[9];
    const float* W2  = (const float*)d_in[10];
    const float* b2  = (const float*)d_in[11];

    float* ws     = (float*)d_ws;
    float* part   = ws + OFF_PART;
    int*   deg    = (int*)(ws + OFF_DEG);
    int*   rowptr = (int*)(ws + OFF_ROWPTR);
    int*   bsums  = (int*)(ws + OFF_BSUMS);
    float4* h0    = (float4*)(ws + OFF_H0);
    int*   csr    = (int*)(ws + OFF_CSR);
    __hip_bfloat16* Wpk2 = (__hip_bfloat16*)(ws + OFF_WPK2);
    __hip_bfloat16* Wpk1 = (__hip_bfloat16*)(ws + OFF_WPK1);
    __hip_bfloat16* W2pk = (__hip_bfloat16*)(ws + OFF_W2PK);
    __hip_bfloat16* Xb   = (__hip_bfloat16*)(ws + OFF_XB);

    const int nb_scan = (N_NODES + 1023) / 1024;   // 98

    stats_partial_k<<<NB_STATS, 256, 0, stream>>>(x, part, deg);
    normalize_k<<<(N_NODES + 255) / 256, 256, 0, stream>>>(x, part, h0,
            Wl2, Wr2, W1, W2, Wpk2, Wpk1, W2pk, ei, deg);
    scan1_k<<<nb_scan, 256, 0, stream>>>(deg, rowptr, bsums);
    scan3_k<<<nb_scan, 256, 0, stream>>>(rowptr, bsums, nb_scan);
    scatter_k<<<(N_EDGES + 255) / 256, 256, 0, stream>>>(ei, rowptr, csr);

    agg1conv1_k<<<(N_NODES + 255) / 256, 256, 0, stream>>>(h0, rowptr, deg, csr,
            Wl1, bl1, Wr1, Xb);
    agg2_k<<<N_NODES / 8, 256, 0, stream>>>(Xb, rowptr, deg, csr);
    conv2mlp_k<<<256, 512, 0, stream>>>(Xb, Wpk2, bl2, Wpk1, b1, W2pk, b2,
            (float*)d_out);
}

// Round 14
// 265.319 us; speedup vs baseline: 1.0840x; 1.0077x over previous
//
#include <hip/hip_runtime.h>
#include <hip/hip_bf16.h>
#include <math.h>

#define N_NODES 100000
#define N_EDGES 600000
#define H 128
#define LH 256
#define CDIM 8
#define NB_STATS 64
#define NT128 ((N_NODES + 127) / 128)   // 782 (128-row tiles, fused kernel)

typedef __attribute__((ext_vector_type(8))) short short8;
typedef __attribute__((ext_vector_type(4))) float floatx4;

// ------------- workspace layout (4-byte words) -------------
#define OFF_PART   0
#define OFF_PARAMS 704
#define OFF_DEG    712
#define OFF_ROWPTR (OFF_DEG + N_NODES)
#define OFF_BSUMS  (OFF_ROWPTR + N_NODES)
#define OFF_H0     (OFF_BSUMS + 128)            // N*4 fp32 (float4 rows)
#define OFF_AGG1   (OFF_H0 + N_NODES*4)         // (unused, kept for layout)
#define OFF_CSR    (OFF_AGG1 + N_NODES*4)
#define OFF_WPK2   (OFF_CSR + N_EDGES)          // 32768 bf16 = 16384 words
#define OFF_WPK1   (OFF_WPK2 + 16384)           // 32768 bf16
#define OFF_W2PK   (OFF_WPK1 + 16384)           // 4096 bf16 = 2048 words
#define OFF_XB     (OFF_W2PK + 2048)            // N*256 bf16 = 12.8M words

__device__ __forceinline__ float rot_c() { return cosf(1.57079632679489661923f); }
__device__ __forceinline__ float rot_s() { return sinf(1.57079632679489661923f); }
__device__ __forceinline__ float bfhi(unsigned v) { return __uint_as_float(v & 0xffff0000u); }
__device__ __forceinline__ float bflo(unsigned v) { return __uint_as_float(v << 16); }
__device__ __forceinline__ unsigned short bfu(float f) {
    __hip_bfloat16 h = __float2bfloat16(f);
    return *(unsigned short*)&h;
}
// fast tanh: 1 - 2/(e^{2x}+1). Exact at +-inf (rcp(inf)=0), rel err ~1e-6,
// far below bf16 quantization (~4e-3). ~5 VALU ops vs ~40 for libm tanhf.
__device__ __forceinline__ float ftanh(float x) {
    float e = __expf(2.0f * x);
    return 1.0f - 2.0f * __builtin_amdgcn_rcpf(e + 1.0f);
}

// ---------------- stats partial (also zeroes deg) ----------------
__global__ void stats_partial_k(const float* __restrict__ x, float* __restrict__ part,
                                int* __restrict__ deg) {
    const float c = rot_c(), sn = rot_s();
    float mn0 = INFINITY, mx0 = -INFINITY, mn1 = INFINITY, mx1 = -INFINITY;
    float s0 = 0.f, s1 = 0.f, sr0 = 0.f, sr1 = 0.f;
    float mxr0 = -INFINITY, mxr1 = -INFINITY, mxa = -INFINITY;
    for (int i = blockIdx.x * blockDim.x + threadIdx.x; i < N_NODES;
         i += gridDim.x * blockDim.x) {
        deg[i] = 0;
        float x0 = x[3*i], x1 = x[3*i+1], a = x[3*i+2];
        float r0 = c*x0 - sn*x1;
        float r1 = sn*x0 + c*x1;
        mn0 = fminf(mn0, x0); mx0 = fmaxf(mx0, x0);
        mn1 = fminf(mn1, x1); mx1 = fmaxf(mx1, x1);
        s0 += x0; s1 += x1; sr0 += r0; sr1 += r1;
        mxr0 = fmaxf(mxr0, r0); mxr1 = fmaxf(mxr1, r1);
        mxa = fmaxf(mxa, a);
    }
    __shared__ float red[256];
    float vals[11] = {mn0, mx0, mn1, mx1, s0, s1, sr0, sr1, mxr0, mxr1, mxa};
    const int ops[11] = {0,1,0,1,2,2,2,2,1,1,1};
    for (int v = 0; v < 11; v++) {
        red[threadIdx.x] = vals[v];
        __syncthreads();
        for (int s = 128; s > 0; s >>= 1) {
            if ((int)threadIdx.x < s) {
                float a = red[threadIdx.x], b = red[threadIdx.x + s];
                red[threadIdx.x] = (ops[v]==0) ? fminf(a,b) : (ops[v]==1) ? fmaxf(a,b) : (a+b);
            }
            __syncthreads();
        }
        if (threadIdx.x == 0) part[blockIdx.x * 11 + v] = red[0];
        __syncthreads();
    }
}

// ---------------- normalize (+ final stats reduce + pre-pack + deg_count) --
// deg was fully zeroed by stats_partial_k (completes before this launches).
__global__ __launch_bounds__(256) void normalize_k(const float* __restrict__ x,
        const float* __restrict__ part, float4* __restrict__ h0,
        const float* __restrict__ Wl2, const float* __restrict__ Wr2,
        const float* __restrict__ W1, const float* __restrict__ W2,
        __hip_bfloat16* __restrict__ Wpk2, __hip_bfloat16* __restrict__ Wpk1,
        __hip_bfloat16* __restrict__ W2pk,
        const int* __restrict__ ei, int* __restrict__ deg) {
    __shared__ float res[11];
    int tid = threadIdx.x;
    if (tid < 64) {
        const int ops[11] = {0,1,0,1,2,2,2,2,1,1,1};
        for (int v = 0; v < 11; v++) {
            float val = part[tid * 11 + v];
            #pragma unroll
            for (int off = 32; off > 0; off >>= 1) {
                float o = __shfl_down(val, off);
                val = (ops[v]==0) ? fminf(val,o) : (ops[v]==1) ? fmaxf(val,o) : (val+o);
            }
            if (tid == 0) res[v] = val;
        }
    }
    __syncthreads();
    int rotate = (res[3] - res[2]) > (res[1] - res[0]);
    float mean0 = (rotate ? res[6] : res[4]) / (float)N_NODES;
    float mean1 = (rotate ? res[7] : res[5]) / (float)N_NODES;
    float imx0  = 1.0f / (rotate ? res[8] : res[1]);
    float imx1  = 1.0f / (rotate ? res[9] : res[3]);
    float imxa  = 1.0f / res[10];

    int i = blockIdx.x * blockDim.x + tid;
    if (i < N_NODES) {
        const float c = rot_c(), sn = rot_s();
        float x0 = x[3*i], x1 = x[3*i+1], a = x[3*i+2];
        float u0 = rotate ? (c*x0 - sn*x1) : x0;
        float u1 = rotate ? (sn*x0 + c*x1) : x1;
        h0[i] = make_float4((u0 - mean0) * imx0, (u1 - mean1) * imx1, a * imxa, 0.f);
    }
    int idx = i;
    if (idx < 32768) {                       // Wpk2[ks8][nt8][lane64][j8], K=256,N=128
        int j = idx & 7, lane = (idx >> 3) & 63, nt = (idx >> 9) & 7, ks = idx >> 12;
        int k = ks*32 + (lane >> 4)*8 + j;
        int n = nt*16 + (lane & 15);
        float v = (k < 128) ? Wl2[n*H + k] : Wr2[n*H + (k - 128)];
        Wpk2[idx] = __float2bfloat16(v);
    } else if (idx < 65536) {                // Wpk1[ks4][nt16][lane64][j8], K=128,N=256
        int i2 = idx - 32768;
        int j = i2 & 7, lane = (i2 >> 3) & 63, nt = (i2 >> 9) & 15, ks = i2 >> 13;
        int k = ks*32 + (lane >> 4)*8 + j;
        int n = nt*16 + (lane & 15);
        Wpk1[i2] = __float2bfloat16(W1[n*H + k]);
    } else if (idx < 69632) {                // W2pk[ks8][lane64][j8], K=256,N=16(8 real)
        int i3 = idx - 65536;
        int j = i3 & 7, lane = (i3 >> 3) & 63, ks = i3 >> 9;
        int k = ks*32 + (lane >> 4)*8 + j;
        int n = lane & 15;
        W2pk[i3] = __float2bfloat16((n < CDIM) ? W2[n*LH + k] : 0.f);
    }
    // folded deg_count: grid-stride over edges (~6 atomics/thread)
    int nthreads = gridDim.x * blockDim.x;
    for (int e = i; e < N_EDGES; e += nthreads)
        atomicAdd(&deg[ei[N_EDGES + e]], 1);
}

// ---------------- CSR build ----------------
__global__ void scan1_k(const int* __restrict__ deg, int* __restrict__ rowptr,
                        int* __restrict__ bsums) {
    __shared__ int s[256];
    int t = threadIdx.x;
    int base = blockIdx.x * 1024 + t * 4;
    int d0 = (base+0 < N_NODES) ? deg[base+0] : 0;
    int d1 = (base+1 < N_NODES) ? deg[base+1] : 0;
    int d2 = (base+2 < N_NODES) ? deg[base+2] : 0;
    int d3 = (base+3 < N_NODES) ? deg[base+3] : 0;
    int tsum = d0 + d1 + d2 + d3;
    s[t] = tsum;
    __syncthreads();
    for (int off = 1; off < 256; off <<= 1) {
        int v = (t >= off) ? s[t - off] : 0;
        __syncthreads();
        s[t] += v;
        __syncthreads();
    }
    int excl = s[t] - tsum;
    if (base+0 < N_NODES) rowptr[base+0] = excl;
    if (base+1 < N_NODES) rowptr[base+1] = excl + d0;
    if (base+2 < N_NODES) rowptr[base+2] = excl + d0 + d1;
    if (base+3 < N_NODES) rowptr[base+3] = excl + d0 + d1 + d2;
    if (t == 255) bsums[blockIdx.x] = s[255];
}

// scan3 with folded scan2: add = sum of bsums[0..blockIdx-1]
__global__ void scan3_k(int* __restrict__ rowptr, const int* __restrict__ bsums, int nb) {
    __shared__ int sb[256];
    int t = threadIdx.x;
    sb[t] = (t < (int)blockIdx.x && t < nb) ? bsums[t] : 0;
    __syncthreads();
    for (int s = 128; s > 0; s >>= 1) {
        if (t < s) sb[t] += sb[t + s];
        __syncthreads();
    }
    int add = sb[0];
    int base = blockIdx.x * 1024 + t * 4;
    if (base+0 < N_NODES) rowptr[base+0] += add;
    if (base+1 < N_NODES) rowptr[base+1] += add;
    if (base+2 < N_NODES) rowptr[base+2] += add;
    if (base+3 < N_NODES) rowptr[base+3] += add;
}

__global__ void scatter_k(const int* __restrict__ ei, int* __restrict__ rowptr,
                          int* __restrict__ csr) {
    int e = blockIdx.x * blockDim.x + threadIdx.x;
    if (e >= N_EDGES) return;
    int d = ei[N_EDGES + e];
    int pos = atomicAdd(&rowptr[d], 1);
    csr[pos] = ei[e];
}

// ---------------- fused agg1 + conv1 dense ----------------
__global__ __launch_bounds__(256) void agg1conv1_k(const float4* __restrict__ h0,
        const int* __restrict__ rowptr, const int* __restrict__ deg,
        const int* __restrict__ csr,
        const float* __restrict__ Wl1, const float* __restrict__ bl1,
        const float* __restrict__ Wr1, __hip_bfloat16* __restrict__ Xb) {
    __shared__ float wl[H*3], wr[H*3], bb[H];
    __shared__ float4 sa[256];
    int tid = threadIdx.x;
    for (int i = tid; i < H*3; i += 256) { wl[i] = Wl1[i]; wr[i] = Wr1[i]; }
    if (tid < H) bb[tid] = bl1[tid];
    int base = blockIdx.x * 256;
    int n = base + tid;
    float4 av = make_float4(0.f, 0.f, 0.f, 0.f);
    if (n < N_NODES) {
        int dg = deg[n];
        int end = rowptr[n], start = end - dg;
        float a0 = 0.f, a1 = 0.f, a2 = 0.f;
        int e = start;
        for (; e + 3 < end; e += 4) {
            int s0 = csr[e], s1 = csr[e+1], s2 = csr[e+2], s3 = csr[e+3];
            float4 v0 = h0[s0];
            float4 v1 = h0[s1];
            float4 v2 = h0[s2];
            float4 v3 = h0[s3];
            a0 += (v0.x + v1.x) + (v2.x + v3.x);
            a1 += (v0.y + v1.y) + (v2.y + v3.y);
            a2 += (v0.z + v1.z) + (v2.z + v3.z);
        }
        for (; e < end; e++) {
            float4 v = h0[csr[e]];
            a0 += v.x; a1 += v.y; a2 += v.z;
        }
        float inv = 1.0f / (float)max(dg, 1);
        av = make_float4(a0 * inv, a1 * inv, a2 * inv, 0.f);
    }
    sa[tid] = av;
    __syncthreads();
    int sub = tid >> 6;
    int j2 = (tid & 63) * 2;
    for (int i = 0; i < 64; i++) {
        int loc = i * 4 + sub;
        int nn = base + loc;
        if (nn >= N_NODES) break;
        float4 a = sa[loc];
        float4 xv = h0[nn];
        float o0 = wl[3*j2+0]*a.x + wl[3*j2+1]*a.y + wl[3*j2+2]*a.z + bb[j2]
                 + wr[3*j2+0]*xv.x + wr[3*j2+1]*xv.y + wr[3*j2+2]*xv.z;
        float o1 = wl[3*j2+3]*a.x + wl[3*j2+4]*a.y + wl[3*j2+5]*a.z + bb[j2+1]
                 + wr[3*j2+3]*xv.x + wr[3*j2+4]*xv.y + wr[3*j2+5]*xv.z;
        unsigned pv = ((unsigned)bfu(ftanh(o1)) << 16) | (unsigned)bfu(ftanh(o0));
        *(unsigned*)&Xb[(size_t)nn*256 + 128 + j2] = pv;
    }
}

// ---------------- agg2: mean of h1 (bf16) -> Xb[n][0..127]
// 16 lanes/node x uint4 (16 B/lane): one instruction covers the full 256-B
// row; 16 nodes per 256-thread block (grid 6250); 8 fp32 accumulators/lane.
__global__ void agg2_k(__hip_bfloat16* __restrict__ Xb, const int* __restrict__ rowptr,
                       const int* __restrict__ deg, const int* __restrict__ csr) {
    int lane = threadIdx.x & 15;
    int n = blockIdx.x * 16 + (threadIdx.x >> 4);
    int dg = deg[n];
    int end = rowptr[n], start = end - dg;
    const short* XbS = (const short*)Xb;
    float a0=0.f,a1=0.f,a2=0.f,a3=0.f,a4=0.f,a5=0.f,a6=0.f,a7=0.f;
    int e = start;
    for (; e + 1 < end; e += 2) {
        int s0 = csr[e], s1 = csr[e+1];
        uint4 v0 = *(const uint4*)&XbS[(size_t)s0*256 + 128 + lane*8];
        uint4 v1 = *(const uint4*)&XbS[(size_t)s1*256 + 128 + lane*8];
        a0 += bflo(v0.x) + bflo(v1.x); a1 += bfhi(v0.x) + bfhi(v1.x);
        a2 += bflo(v0.y) + bflo(v1.y); a3 += bfhi(v0.y) + bfhi(v1.y);
        a4 += bflo(v0.z) + bflo(v1.z); a5 += bfhi(v0.z) + bfhi(v1.z);
        a6 += bflo(v0.w) + bflo(v1.w); a7 += bfhi(v0.w) + bfhi(v1.w);
    }
    if (e < end) {
        int s0 = csr[e];
        uint4 v0 = *(const uint4*)&XbS[(size_t)s0*256 + 128 + lane*8];
        a0 += bflo(v0.x); a1 += bfhi(v0.x);
        a2 += bflo(v0.y); a3 += bfhi(v0.y);
        a4 += bflo(v0.z); a5 += bfhi(v0.z);
        a6 += bflo(v0.w); a7 += bfhi(v0.w);
    }
    float inv = 1.0f / (float)max(dg, 1);
    uint4 o;
    o.x = ((unsigned)bfu(a1*inv) << 16) | (unsigned)bfu(a0*inv);
    o.y = ((unsigned)bfu(a3*inv) << 16) | (unsigned)bfu(a2*inv);
    o.z = ((unsigned)bfu(a5*inv) << 16) | (unsigned)bfu(a4*inv);
    o.w = ((unsigned)bfu(a7*inv) << 16) | (unsigned)bfu(a6*inv);
    *(uint4*)&Xb[(size_t)n*256 + lane*8] = o;
}

// ---------------- FUSED conv2 + MLP + softmax (8 waves, 2/SIMD) ----------
// 512 threads share Ws2+Ws1 (128 KB); per-wave 16x128 staging slice with XOR
// swizzle (group' = group ^ row at 16B granularity) -> no padding, 32 KB.
// Total LDS = 160 KB = 1 block/CU = 8 waves/CU = 2 waves/SIMD.
// Cs index (shorts): row*128 + ((colgrp ^ row)<<3) + (col&7), colgrp = col>>3.
__global__ __launch_bounds__(512, 1) void conv2mlp_k(const __hip_bfloat16* __restrict__ Xb,
        const __hip_bfloat16* __restrict__ Wpk2, const float* __restrict__ bl2,
        const __hip_bfloat16* __restrict__ Wpk1, const float* __restrict__ b1,
        const __hip_bfloat16* __restrict__ W2pk, const float* __restrict__ b2,
        float* __restrict__ out) {
    __shared__ short Ws2[32768];         // conv2 weights [ks8][nt8][lane64][j8]
    __shared__ short Ws1[32768];         // W1 weights [ks4][nt16][lane64][j8]
    __shared__ short Cs[8 * 16 * 128];   // per-wave 16x128 swizzled staging
    int tid = threadIdx.x;
    int lane = tid & 63, wave = tid >> 6;
    int quad = lane >> 4, m = lane & 15, c0 = lane & 15;
    {
        // 512 threads x 8 iters x 16 B = exactly 64 KB per array
        const float4* s2 = (const float4*)Wpk2;
        const float4* s1 = (const float4*)Wpk1;
        float4* d2 = (float4*)Ws2;
        float4* d1 = (float4*)Ws1;
        #pragma unroll
        for (int i = 0; i < 8; i++) {
            d2[tid + i*512] = s2[tid + i*512];
            d1[tid + i*512] = s1[tid + i*512];
        }
    }
    // W2 fragments + biases -> registers (persistent)
    short8 w2f[8];
    #pragma unroll
    for (int ks = 0; ks < 8; ks++)
        w2f[ks] = *(const short8*)&W2pk[(ks*64 + lane)*8];
    float bl2r[8], b1r[16];
    #pragma unroll
    for (int nt = 0; nt < 8; nt++) bl2r[nt] = bl2[nt*16 + c0];
    #pragma unroll
    for (int nt = 0; nt < 16; nt++) b1r[nt] = b1[nt*16 + c0];
    float b2v = (c0 < CDIM) ? b2[c0] : 0.f;
    __syncthreads();
    short* Tw = &Cs[wave * (16 * 128)];

    int tile = blockIdx.x;
    short8 areg[8];
    {
        int row = tile*128 + wave*16 + m;
        int rowL = row < N_NODES ? row : N_NODES - 1;
        const short* Arow = (const short*)Xb + (size_t)rowL * 256;
        #pragma unroll
        for (int ks = 0; ks < 8; ks++)
            areg[ks] = *(const short8*)(Arow + ks*32 + quad*8);
    }
    for (; tile < NT128; tile += gridDim.x) {
        // prefetch next tile's A fragments
        short8 anext[8];
        {
            int tnext = tile + gridDim.x;
            int rown = (tnext < NT128) ? (tnext*128 + wave*16 + m) : 0;
            int rowNL = rown < N_NODES ? rown : N_NODES - 1;
            const short* ArowN = (const short*)Xb + (size_t)rowNL * 256;
            #pragma unroll
            for (int ks = 0; ks < 8; ks++)
                anext[ks] = *(const short8*)(ArowN + ks*32 + quad*8);
        }
        // ---- conv2: h2 = tanh([agg2|h1] @ W' + bl2)
        floatx4 acc2[8];
        #pragma unroll
        for (int i = 0; i < 8; i++)
            #pragma unroll
            for (int r = 0; r < 4; r++) acc2[i][r] = 0.f;
        #pragma unroll
        for (int ks = 0; ks < 8; ks++) {
            #pragma unroll
            for (int nt = 0; nt < 8; nt++) {
                short8 b = *(const short8*)&Ws2[((ks*8 + nt)*64 + lane)*8];
                acc2[nt] = __builtin_amdgcn_mfma_f32_16x16x32_bf16(areg[ks], b, acc2[nt], 0, 0, 0);
            }
        }
        #pragma unroll
        for (int nt = 0; nt < 8; nt++) {
            int cg = nt*2 + (c0 >> 3);
            #pragma unroll
            for (int r = 0; r < 4; r++) {
                int row = quad*4 + r;
                Tw[row*128 + ((cg ^ row) << 3) + (c0 & 7)] =
                    (short)bfu(ftanh(acc2[nt][r] + bl2r[nt]));
            }
        }
        // ---- GEMM1: t_pre = h2 @ W1^T  (A from the slice just written)
        floatx4 acc1[16];
        #pragma unroll
        for (int i = 0; i < 16; i++)
            #pragma unroll
            for (int r = 0; r < 4; r++) acc1[i][r] = 0.f;
        #pragma unroll
        for (int ks = 0; ks < 4; ks++) {
            short8 a = *(const short8*)&Tw[m*128 + (((ks*4 + quad) ^ m) << 3)];
            #pragma unroll
            for (int nt = 0; nt < 16; nt++) {
                short8 b = *(const short8*)&Ws1[((ks*16 + nt)*64 + lane)*8];
                acc1[nt] = __builtin_amdgcn_mfma_f32_16x16x32_bf16(a, b, acc1[nt], 0, 0, 0);
            }
        }
        // ---- GEMM2 in 4 K-chunks through the (now dead) slice
        floatx4 lacc;
        #pragma unroll
        for (int r = 0; r < 4; r++) lacc[r] = 0.f;
        #pragma unroll
        for (int ch = 0; ch < 4; ch++) {
            #pragma unroll
            for (int ntl = 0; ntl < 4; ntl++) {
                int nt = ch*4 + ntl;
                int cg = ntl*2 + (c0 >> 3);
                #pragma unroll
                for (int r = 0; r < 4; r++) {
                    int row = quad*4 + r;
                    Tw[row*128 + ((cg ^ row) << 3) + (c0 & 7)] =
                        (short)bfu(ftanh(acc1[nt][r] + b1r[nt]));
                }
            }
            #pragma unroll
            for (int k2 = 0; k2 < 2; k2++) {
                short8 a = *(const short8*)&Tw[m*128 + (((k2*4 + quad) ^ m) << 3)];
                lacc = __builtin_amdgcn_mfma_f32_16x16x32_bf16(a, w2f[ch*2 + k2], lacc, 0, 0, 0);
            }
        }
        // ---- softmax across the 8 class lanes
        int rbase = tile*128 + wave*16 + quad*4;
        #pragma unroll
        for (int r = 0; r < 4; r++) {
            float v = lacc[r] + b2v;
            float mval = (c0 < CDIM) ? v : -INFINITY;
            #pragma unroll
            for (int off = 1; off < 8; off <<= 1)
                mval = fmaxf(mval, __shfl_xor(mval, off));
            float e = (c0 < CDIM) ? __expf(v - mval) : 0.f;
            float ssum = e;
            #pragma unroll
            for (int off = 1; off < 8; off <<= 1)
                ssum += __shfl_xor(ssum, off);
            int rowg = rbase + r;
            if (c0 < CDIM && rowg < N_NODES)
                out[(size_t)rowg*CDIM + c0] = e / ssum;
        }
        #pragma unroll
        for (int ks = 0; ks < 8; ks++) areg[ks] = anext[ks];
    }
}

extern "C" void kernel_launch(void* const* d_in, const int* in_sizes, int n_in,
                              void* d_out, int out_size, void* d_ws, size_t ws_size,
                              hipStream_t stream) {
    const float* x   = (const float*)d_in[0];
    const int*   ei  = (const int*)d_in[1];
    const float* Wl1 = (const float*)d_in[2];
    const float* bl1 = (const float*)d_in[3];
    const float* Wr1 = (const float*)d_in[4];
    const float* Wl2 = (const float*)d_in[5];
    const float* bl2 = (const float*)d_in[6];
    const float* Wr2 = (const float*)d_in[7];
    const float* W1  = (const float*)d_in[8];
    const float* b1  = (const float*)d_in[9];
    const float* W2  = (const float*)d_in[10];
    const float* b2  = (const float*)d_in[11];

    float* ws     = (float*)d_ws;
    float* part   = ws + OFF_PART;
    int*   deg    = (int*)(ws + OFF_DEG);
    int*   rowptr = (int*)(ws + OFF_ROWPTR);
    int*   bsums  = (int*)(ws + OFF_BSUMS);
    float4* h0    = (float4*)(ws + OFF_H0);
    int*   csr    = (int*)(ws + OFF_CSR);
    __hip_bfloat16* Wpk2 = (__hip_bfloat16*)(ws + OFF_WPK2);
    __hip_bfloat16* Wpk1 = (__hip_bfloat16*)(ws + OFF_WPK1);
    __hip_bfloat16* W2pk = (__hip_bfloat16*)(ws + OFF_W2PK);
    __hip_bfloat16* Xb   = (__hip_bfloat16*)(ws + OFF_XB);

    const int nb_scan = (N_NODES + 1023) / 1024;   // 98

    stats_partial_k<<<NB_STATS, 256, 0, stream>>>(x, part, deg);
    normalize_k<<<(N_NODES + 255) / 256, 256, 0, stream>>>(x, part, h0,
            Wl2, Wr2, W1, W2, Wpk2, Wpk1, W2pk, ei, deg);
    scan1_k<<<nb_scan, 256, 0, stream>>>(deg, rowptr, bsums);
    scan3_k<<<nb_scan, 256, 0, stream>>>(rowptr, bsums, nb_scan);
    scatter_k<<<(N_EDGES + 255) / 256, 256, 0, stream>>>(ei, rowptr, csr);

    agg1conv1_k<<<(N_NODES + 255) / 256, 256, 0, stream>>>(h0, rowptr, deg, csr,
            Wl1, bl1, Wr1, Xb);
    agg2_k<<<N_NODES / 16, 256, 0, stream>>>(Xb, rowptr, deg, csr);
    conv2mlp_k<<<256, 512, 0, stream>>>(Xb, Wpk2, bl2, Wpk1, b1, W2pk, b2,
            (float*)d_out);
}

// Round 15
// 265.104 us; speedup vs baseline: 1.0849x; 1.0008x over previous
//
#include <hip/hip_runtime.h>
#include <hip/hip_bf16.h>
#include <math.h>

#define N_NODES 100000
#define N_EDGES 600000
#define H 128
#define LH 256
#define CDIM 8
#define NB_STATS 256
#define NT128 ((N_NODES + 127) / 128)   // 782 (128-row tiles, fused kernel)

typedef __attribute__((ext_vector_type(8))) short short8;
typedef __attribute__((ext_vector_type(4))) float floatx4;

// ------------- workspace layout (4-byte words) -------------
#define OFF_PART   0                                  // 256*11 = 2816
#define OFF_CNT    2816                               // 1 (alloc counter)
#define OFF_DEG    2820
#define OFF_ROWPTR (OFF_DEG + N_NODES)
#define OFF_H0     (OFF_ROWPTR + N_NODES)             // 202820, /4 ok -> 16B aligned
#define OFF_CSR    (OFF_H0 + N_NODES*4)
#define OFF_WPK2   (OFF_CSR + N_EDGES)                // 16B aligned
#define OFF_WPK1   (OFF_WPK2 + 16384)
#define OFF_W2PK   (OFF_WPK1 + 16384)
#define OFF_XB     (OFF_W2PK + 2048)
// end ~= 14.04M words = 56.2 MB (< 103 MB proven)

__device__ __forceinline__ float rot_c() { return cosf(1.57079632679489661923f); }
__device__ __forceinline__ float rot_s() { return sinf(1.57079632679489661923f); }
__device__ __forceinline__ float bfhi(unsigned v) { return __uint_as_float(v & 0xffff0000u); }
__device__ __forceinline__ float bflo(unsigned v) { return __uint_as_float(v << 16); }
__device__ __forceinline__ unsigned short bfu(float f) {
    __hip_bfloat16 h = __float2bfloat16(f);
    return *(unsigned short*)&h;
}
// fast tanh: 1 - 2/(e^{2x}+1). Exact at +-inf (rcp(inf)=0), rel err ~1e-6,
// far below bf16 quantization (~4e-3). ~5 VALU ops vs ~40 for libm tanhf.
__device__ __forceinline__ float ftanh(float x) {
    float e = __expf(2.0f * x);
    return 1.0f - 2.0f * __builtin_amdgcn_rcpf(e + 1.0f);
}

// ---------------- stats partial (also zeroes deg + alloc counter) ---------
__global__ void stats_partial_k(const float* __restrict__ x, float* __restrict__ part,
                                int* __restrict__ deg, int* __restrict__ cnt) {
    if (blockIdx.x == 0 && threadIdx.x == 0) *cnt = 0;
    const float c = rot_c(), sn = rot_s();
    float mn0 = INFINITY, mx0 = -INFINITY, mn1 = INFINITY, mx1 = -INFINITY;
    float s0 = 0.f, s1 = 0.f, sr0 = 0.f, sr1 = 0.f;
    float mxr0 = -INFINITY, mxr1 = -INFINITY, mxa = -INFINITY;
    for (int i = blockIdx.x * blockDim.x + threadIdx.x; i < N_NODES;
         i += gridDim.x * blockDim.x) {
        deg[i] = 0;
        float x0 = x[3*i], x1 = x[3*i+1], a = x[3*i+2];
        float r0 = c*x0 - sn*x1;
        float r1 = sn*x0 + c*x1;
        mn0 = fminf(mn0, x0); mx0 = fmaxf(mx0, x0);
        mn1 = fminf(mn1, x1); mx1 = fmaxf(mx1, x1);
        s0 += x0; s1 += x1; sr0 += r0; sr1 += r1;
        mxr0 = fmaxf(mxr0, r0); mxr1 = fmaxf(mxr1, r1);
        mxa = fmaxf(mxa, a);
    }
    __shared__ float red[256];
    float vals[11] = {mn0, mx0, mn1, mx1, s0, s1, sr0, sr1, mxr0, mxr1, mxa};
    const int ops[11] = {0,1,0,1,2,2,2,2,1,1,1};
    for (int v = 0; v < 11; v++) {
        red[threadIdx.x] = vals[v];
        __syncthreads();
        for (int s = 128; s > 0; s >>= 1) {
            if ((int)threadIdx.x < s) {
                float a = red[threadIdx.x], b = red[threadIdx.x + s];
                red[threadIdx.x] = (ops[v]==0) ? fminf(a,b) : (ops[v]==1) ? fmaxf(a,b) : (a+b);
            }
            __syncthreads();
        }
        if (threadIdx.x == 0) part[blockIdx.x * 11 + v] = red[0];
        __syncthreads();
    }
}

// ---------------- normalize (+ final stats reduce + pre-pack + deg_count) --
// deg was fully zeroed by stats_partial_k (completes before this launches).
// Launched with 1024 blocks: node/pack work guarded, edge histogram gets
// 262K threads (shorter atomic tail on the critical path).
__global__ __launch_bounds__(256) void normalize_k(const float* __restrict__ x,
        const float* __restrict__ part, float4* __restrict__ h0,
        const float* __restrict__ Wl2, const float* __restrict__ Wr2,
        const float* __restrict__ W1, const float* __restrict__ W2,
        __hip_bfloat16* __restrict__ Wpk2, __hip_bfloat16* __restrict__ Wpk1,
        __hip_bfloat16* __restrict__ W2pk,
        const int* __restrict__ ei, int* __restrict__ deg) {
    __shared__ float res[11];
    int tid = threadIdx.x;
    if (tid < 64) {
        const int ops[11] = {0,1,0,1,2,2,2,2,1,1,1};
        for (int v = 0; v < 11; v++) {
            float val = part[tid * 11 + v];
            #pragma unroll
            for (int p = 1; p < 4; p++) {
                float o = part[(tid + p*64) * 11 + v];
                val = (ops[v]==0) ? fminf(val,o) : (ops[v]==1) ? fmaxf(val,o) : (val+o);
            }
            #pragma unroll
            for (int off = 32; off > 0; off >>= 1) {
                float o = __shfl_down(val, off);
                val = (ops[v]==0) ? fminf(val,o) : (ops[v]==1) ? fmaxf(val,o) : (val+o);
            }
            if (tid == 0) res[v] = val;
        }
    }
    __syncthreads();
    int rotate = (res[3] - res[2]) > (res[1] - res[0]);
    float mean0 = (rotate ? res[6] : res[4]) / (float)N_NODES;
    float mean1 = (rotate ? res[7] : res[5]) / (float)N_NODES;
    float imx0  = 1.0f / (rotate ? res[8] : res[1]);
    float imx1  = 1.0f / (rotate ? res[9] : res[3]);
    float imxa  = 1.0f / res[10];

    int i = blockIdx.x * blockDim.x + tid;
    if (i < N_NODES) {
        const float c = rot_c(), sn = rot_s();
        float x0 = x[3*i], x1 = x[3*i+1], a = x[3*i+2];
        float u0 = rotate ? (c*x0 - sn*x1) : x0;
        float u1 = rotate ? (sn*x0 + c*x1) : x1;
        h0[i] = make_float4((u0 - mean0) * imx0, (u1 - mean1) * imx1, a * imxa, 0.f);
    }
    int idx = i;
    if (idx < 32768) {                       // Wpk2[ks8][nt8][lane64][j8], K=256,N=128
        int j = idx & 7, lane = (idx >> 3) & 63, nt = (idx >> 9) & 7, ks = idx >> 12;
        int k = ks*32 + (lane >> 4)*8 + j;
        int n = nt*16 + (lane & 15);
        float v = (k < 128) ? Wl2[n*H + k] : Wr2[n*H + (k - 128)];
        Wpk2[idx] = __float2bfloat16(v);
    } else if (idx < 65536) {                // Wpk1[ks4][nt16][lane64][j8], K=128,N=256
        int i2 = idx - 32768;
        int j = i2 & 7, lane = (i2 >> 3) & 63, nt = (i2 >> 9) & 15, ks = i2 >> 13;
        int k = ks*32 + (lane >> 4)*8 + j;
        int n = nt*16 + (lane & 15);
        Wpk1[i2] = __float2bfloat16(W1[n*H + k]);
    } else if (idx < 69632) {                // W2pk[ks8][lane64][j8], K=256,N=16(8 real)
        int i3 = idx - 65536;
        int j = i3 & 7, lane = (i3 >> 3) & 63, ks = i3 >> 9;
        int k = ks*32 + (lane >> 4)*8 + j;
        int n = lane & 15;
        W2pk[i3] = __float2bfloat16((n < CDIM) ? W2[n*LH + k] : 0.f);
    }
    // folded deg_count: grid-stride over edges
    int nthreads = gridDim.x * blockDim.x;
    for (int e = i; e < N_EDGES; e += nthreads)
        atomicAdd(&deg[ei[N_EDGES + e]], 1);
}

// ---------------- CSR alloc: local scan + atomic block base ----------------
// rowptr[n] = start of node n's CSR segment. Segment ORDER is
// nondeterministic (atomic base), but each node's own (start,deg) pair is
// consistent, which is all consumers use. Replaces scan1+scan3.
__global__ void alloc_k(const int* __restrict__ deg, int* __restrict__ rowptr,
                        int* __restrict__ cnt) {
    __shared__ int s[256];
    __shared__ int gbase;
    int t = threadIdx.x;
    int base = blockIdx.x * 1024 + t * 4;
    int d0 = (base+0 < N_NODES) ? deg[base+0] : 0;
    int d1 = (base+1 < N_NODES) ? deg[base+1] : 0;
    int d2 = (base+2 < N_NODES) ? deg[base+2] : 0;
    int d3 = (base+3 < N_NODES) ? deg[base+3] : 0;
    int tsum = d0 + d1 + d2 + d3;
    s[t] = tsum;
    __syncthreads();
    for (int off = 1; off < 256; off <<= 1) {
        int v = (t >= off) ? s[t - off] : 0;
        __syncthreads();
        s[t] += v;
        __syncthreads();
    }
    if (t == 255) gbase = atomicAdd(cnt, s[255]);
    __syncthreads();
    int excl = gbase + s[t] - tsum;
    if (base+0 < N_NODES) rowptr[base+0] = excl;
    if (base+1 < N_NODES) rowptr[base+1] = excl + d0;
    if (base+2 < N_NODES) rowptr[base+2] = excl + d0 + d1;
    if (base+3 < N_NODES) rowptr[base+3] = excl + d0 + d1 + d2;
}

__global__ void scatter_k(const int* __restrict__ ei, int* __restrict__ rowptr,
                          int* __restrict__ csr) {
    int e = blockIdx.x * blockDim.x + threadIdx.x;
    if (e >= N_EDGES) return;
    int d = ei[N_EDGES + e];
    int pos = atomicAdd(&rowptr[d], 1);
    csr[pos] = ei[e];
}

// ---------------- fused agg1 + conv1 dense ----------------
__global__ __launch_bounds__(256) void agg1conv1_k(const float4* __restrict__ h0,
        const int* __restrict__ rowptr, const int* __restrict__ deg,
        const int* __restrict__ csr,
        const float* __restrict__ Wl1, const float* __restrict__ bl1,
        const float* __restrict__ Wr1, __hip_bfloat16* __restrict__ Xb) {
    __shared__ float wl[H*3], wr[H*3], bb[H];
    __shared__ float4 sa[256];
    int tid = threadIdx.x;
    for (int i = tid; i < H*3; i += 256) { wl[i] = Wl1[i]; wr[i] = Wr1[i]; }
    if (tid < H) bb[tid] = bl1[tid];
    int base = blockIdx.x * 256;
    int n = base + tid;
    float4 av = make_float4(0.f, 0.f, 0.f, 0.f);
    if (n < N_NODES) {
        int dg = deg[n];
        int end = rowptr[n], start = end - dg;
        float a0 = 0.f, a1 = 0.f, a2 = 0.f;
        int e = start;
        for (; e + 3 < end; e += 4) {
            int s0 = csr[e], s1 = csr[e+1], s2 = csr[e+2], s3 = csr[e+3];
            float4 v0 = h0[s0];
            float4 v1 = h0[s1];
            float4 v2 = h0[s2];
            float4 v3 = h0[s3];
            a0 += (v0.x + v1.x) + (v2.x + v3.x);
            a1 += (v0.y + v1.y) + (v2.y + v3.y);
            a2 += (v0.z + v1.z) + (v2.z + v3.z);
        }
        for (; e < end; e++) {
            float4 v = h0[csr[e]];
            a0 += v.x; a1 += v.y; a2 += v.z;
        }
        float inv = 1.0f / (float)max(dg, 1);
        av = make_float4(a0 * inv, a1 * inv, a2 * inv, 0.f);
    }
    sa[tid] = av;
    __syncthreads();
    int sub = tid >> 6;
    int j2 = (tid & 63) * 2;
    for (int i = 0; i < 64; i++) {
        int loc = i * 4 + sub;
        int nn = base + loc;
        if (nn >= N_NODES) break;
        float4 a = sa[loc];
        float4 xv = h0[nn];
        float o0 = wl[3*j2+0]*a.x + wl[3*j2+1]*a.y + wl[3*j2+2]*a.z + bb[j2]
                 + wr[3*j2+0]*xv.x + wr[3*j2+1]*xv.y + wr[3*j2+2]*xv.z;
        float o1 = wl[3*j2+3]*a.x + wl[3*j2+4]*a.y + wl[3*j2+5]*a.z + bb[j2+1]
                 + wr[3*j2+3]*xv.x + wr[3*j2+4]*xv.y + wr[3*j2+5]*xv.z;
        unsigned pv = ((unsigned)bfu(ftanh(o1)) << 16) | (unsigned)bfu(ftanh(o0));
        *(unsigned*)&Xb[(size_t)nn*256 + 128 + j2] = pv;
    }
}

// ---------------- agg2: mean of h1 (bf16) -> Xb[n][0..127]
// 16 lanes/node x uint4 (16 B/lane): one instruction covers the full 256-B
// row; 16 nodes per 256-thread block (grid 6250); 8 fp32 accumulators/lane.
__global__ void agg2_k(__hip_bfloat16* __restrict__ Xb, const int* __restrict__ rowptr,
                       const int* __restrict__ deg, const int* __restrict__ csr) {
    int lane = threadIdx.x & 15;
    int n = blockIdx.x * 16 + (threadIdx.x >> 4);
    int dg = deg[n];
    int end = rowptr[n], start = end - dg;
    const short* XbS = (const short*)Xb;
    float a0=0.f,a1=0.f,a2=0.f,a3=0.f,a4=0.f,a5=0.f,a6=0.f,a7=0.f;
    int e = start;
    for (; e + 1 < end; e += 2) {
        int s0 = csr[e], s1 = csr[e+1];
        uint4 v0 = *(const uint4*)&XbS[(size_t)s0*256 + 128 + lane*8];
        uint4 v1 = *(const uint4*)&XbS[(size_t)s1*256 + 128 + lane*8];
        a0 += bflo(v0.x) + bflo(v1.x); a1 += bfhi(v0.x) + bfhi(v1.x);
        a2 += bflo(v0.y) + bflo(v1.y); a3 += bfhi(v0.y) + bfhi(v1.y);
        a4 += bflo(v0.z) + bflo(v1.z); a5 += bfhi(v0.z) + bfhi(v1.z);
        a6 += bflo(v0.w) + bflo(v1.w); a7 += bfhi(v0.w) + bfhi(v1.w);
    }
    if (e < end) {
        int s0 = csr[e];
        uint4 v0 = *(const uint4*)&XbS[(size_t)s0*256 + 128 + lane*8];
        a0 += bflo(v0.x); a1 += bfhi(v0.x);
        a2 += bflo(v0.y); a3 += bfhi(v0.y);
        a4 += bflo(v0.z); a5 += bfhi(v0.z);
        a6 += bflo(v0.w); a7 += bfhi(v0.w);
    }
    float inv = 1.0f / (float)max(dg, 1);
    uint4 o;
    o.x = ((unsigned)bfu(a1*inv) << 16) | (unsigned)bfu(a0*inv);
    o.y = ((unsigned)bfu(a3*inv) << 16) | (unsigned)bfu(a2*inv);
    o.z = ((unsigned)bfu(a5*inv) << 16) | (unsigned)bfu(a4*inv);
    o.w = ((unsigned)bfu(a7*inv) << 16) | (unsigned)bfu(a6*inv);
    *(uint4*)&Xb[(size_t)n*256 + lane*8] = o;
}

// ---------------- FUSED conv2 + MLP + softmax (8 waves, 2/SIMD) ----------
// 512 threads share Ws2+Ws1 (128 KB); per-wave 16x128 staging slice with XOR
// swizzle (group' = group ^ row at 16B granularity) -> no padding, 32 KB.
// Total LDS = 160 KB = 1 block/CU = 8 waves/CU = 2 waves/SIMD.
// Cs index (shorts): row*128 + ((colgrp ^ row)<<3) + (col&7), colgrp = col>>3.
__global__ __launch_bounds__(512, 1) void conv2mlp_k(const __hip_bfloat16* __restrict__ Xb,
        const __hip_bfloat16* __restrict__ Wpk2, const float* __restrict__ bl2,
        const __hip_bfloat16* __restrict__ Wpk1, const float* __restrict__ b1,
        const __hip_bfloat16* __restrict__ W2pk, const float* __restrict__ b2,
        float* __restrict__ out) {
    __shared__ short Ws2[32768];         // conv2 weights [ks8][nt8][lane64][j8]
    __shared__ short Ws1[32768];         // W1 weights [ks4][nt16][lane64][j8]
    __shared__ short Cs[8 * 16 * 128];   // per-wave 16x128 swizzled staging
    int tid = threadIdx.x;
    int lane = tid & 63, wave = tid >> 6;
    int quad = lane >> 4, m = lane & 15, c0 = lane & 15;
    {
        // 512 threads x 8 iters x 16 B = exactly 64 KB per array
        const float4* s2 = (const float4*)Wpk2;
        const float4* s1 = (const float4*)Wpk1;
        float4* d2 = (float4*)Ws2;
        float4* d1 = (float4*)Ws1;
        #pragma unroll
        for (int i = 0; i < 8; i++) {
            d2[tid + i*512] = s2[tid + i*512];
            d1[tid + i*512] = s1[tid + i*512];
        }
    }
    // W2 fragments + biases -> registers (persistent)
    short8 w2f[8];
    #pragma unroll
    for (int ks = 0; ks < 8; ks++)
        w2f[ks] = *(const short8*)&W2pk[(ks*64 + lane)*8];
    float bl2r[8], b1r[16];
    #pragma unroll
    for (int nt = 0; nt < 8; nt++) bl2r[nt] = bl2[nt*16 + c0];
    #pragma unroll
    for (int nt = 0; nt < 16; nt++) b1r[nt] = b1[nt*16 + c0];
    float b2v = (c0 < CDIM) ? b2[c0] : 0.f;
    __syncthreads();
    short* Tw = &Cs[wave * (16 * 128)];

    int tile = blockIdx.x;
    short8 areg[8];
    {
        int row = tile*128 + wave*16 + m;
        int rowL = row < N_NODES ? row : N_NODES - 1;
        const short* Arow = (const short*)Xb + (size_t)rowL * 256;
        #pragma unroll
        for (int ks = 0; ks < 8; ks++)
            areg[ks] = *(const short8*)(Arow + ks*32 + quad*8);
    }
    for (; tile < NT128; tile += gridDim.x) {
        // prefetch next tile's A fragments
        short8 anext[8];
        {
            int tnext = tile + gridDim.x;
            int rown = (tnext < NT128) ? (tnext*128 + wave*16 + m) : 0;
            int rowNL = rown < N_NODES ? rown : N_NODES - 1;
            const short* ArowN = (const short*)Xb + (size_t)rowNL * 256;
            #pragma unroll
            for (int ks = 0; ks < 8; ks++)
                anext[ks] = *(const short8*)(ArowN + ks*32 + quad*8);
        }
        // ---- conv2: h2 = tanh([agg2|h1] @ W' + bl2)
        floatx4 acc2[8];
        #pragma unroll
        for (int i = 0; i < 8; i++)
            #pragma unroll
            for (int r = 0; r < 4; r++) acc2[i][r] = 0.f;
        #pragma unroll
        for (int ks = 0; ks < 8; ks++) {
            #pragma unroll
            for (int nt = 0; nt < 8; nt++) {
                short8 b = *(const short8*)&Ws2[((ks*8 + nt)*64 + lane)*8];
                acc2[nt] = __builtin_amdgcn_mfma_f32_16x16x32_bf16(areg[ks], b, acc2[nt], 0, 0, 0);
            }
        }
        #pragma unroll
        for (int nt = 0; nt < 8; nt++) {
            int cg = nt*2 + (c0 >> 3);
            #pragma unroll
            for (int r = 0; r < 4; r++) {
                int row = quad*4 + r;
                Tw[row*128 + ((cg ^ row) << 3) + (c0 & 7)] =
                    (short)bfu(ftanh(acc2[nt][r] + bl2r[nt]));
            }
        }
        // ---- GEMM1: t_pre = h2 @ W1^T  (A from the slice just written)
        floatx4 acc1[16];
        #pragma unroll
        for (int i = 0; i < 16; i++)
            #pragma unroll
            for (int r = 0; r < 4; r++) acc1[i][r] = 0.f;
        #pragma unroll
        for (int ks = 0; ks < 4; ks++) {
            short8 a = *(const short8*)&Tw[m*128 + (((ks*4 + quad) ^ m) << 3)];
            #pragma unroll
            for (int nt = 0; nt < 16; nt++) {
                short8 b = *(const short8*)&Ws1[((ks*16 + nt)*64 + lane)*8];
                acc1[nt] = __builtin_amdgcn_mfma_f32_16x16x32_bf16(a, b, acc1[nt], 0, 0, 0);
            }
        }
        // ---- GEMM2 in 4 K-chunks through the (now dead) slice
        floatx4 lacc;
        #pragma unroll
        for (int r = 0; r < 4; r++) lacc[r] = 0.f;
        #pragma unroll
        for (int ch = 0; ch < 4; ch++) {
            #pragma unroll
            for (int ntl = 0; ntl < 4; ntl++) {
                int nt = ch*4 + ntl;
                int cg = ntl*2 + (c0 >> 3);
                #pragma unroll
                for (int r = 0; r < 4; r++) {
                    int row = quad*4 + r;
                    Tw[row*128 + ((cg ^ row) << 3) + (c0 & 7)] =
                        (short)bfu(ftanh(acc1[nt][r] + b1r[nt]));
                }
            }
            #pragma unroll
            for (int k2 = 0; k2 < 2; k2++) {
                short8 a = *(const short8*)&Tw[m*128 + (((k2*4 + quad) ^ m) << 3)];
                lacc = __builtin_amdgcn_mfma_f32_16x16x32_bf16(a, w2f[ch*2 + k2], lacc, 0, 0, 0);
            }
        }
        // ---- softmax across the 8 class lanes
        int rbase = tile*128 + wave*16 + quad*4;
        #pragma unroll
        for (int r = 0; r < 4; r++) {
            float v = lacc[r] + b2v;
            float mval = (c0 < CDIM) ? v : -INFINITY;
            #pragma unroll
            for (int off = 1; off < 8; off <<= 1)
                mval = fmaxf(mval, __shfl_xor(mval, off));
            float e = (c0 < CDIM) ? __expf(v - mval) : 0.f;
            float ssum = e;
            #pragma unroll
            for (int off = 1; off < 8; off <<= 1)
                ssum += __shfl_xor(ssum, off);
            int rowg = rbase + r;
            if (c0 < CDIM && rowg < N_NODES)
                out[(size_t)rowg*CDIM + c0] = e / ssum;
        }
        #pragma unroll
        for (int ks = 0; ks < 8; ks++) areg[ks] = anext[ks];
    }
}

extern "C" void kernel_launch(void* const* d_in, const int* in_sizes, int n_in,
                              void* d_out, int out_size, void* d_ws, size_t ws_size,
                              hipStream_t stream) {
    const float* x   = (const float*)d_in[0];
    const int*   ei  = (const int*)d_in[1];
    const float* Wl1 = (const float*)d_in[2];
    const float* bl1 = (const float*)d_in[3];
    const float* Wr1 = (const float*)d_in[4];
    const float* Wl2 = (const float*)d_in[5];
    const float* bl2 = (const float*)d_in[6];
    const float* Wr2 = (const float*)d_in[7];
    const float* W1  = (const float*)d_in[8];
    const float* b1  = (const float*)d_in[9];
    const float* W2  = (const float*)d_in[10];
    const float* b2  = (const float*)d_in[11];

    float* ws     = (float*)d_ws;
    float* part   = ws + OFF_PART;
    int*   cnt    = (int*)(ws + OFF_CNT);
    int*   deg    = (int*)(ws + OFF_DEG);
    int*   rowptr = (int*)(ws + OFF_ROWPTR);
    float4* h0    = (float4*)(ws + OFF_H0);
    int*   csr    = (int*)(ws + OFF_CSR);
    __hip_bfloat16* Wpk2 = (__hip_bfloat16*)(ws + OFF_WPK2);
    __hip_bfloat16* Wpk1 = (__hip_bfloat16*)(ws + OFF_WPK1);
    __hip_bfloat16* W2pk = (__hip_bfloat16*)(ws + OFF_W2PK);
    __hip_bfloat16* Xb   = (__hip_bfloat16*)(ws + OFF_XB);

    const int nb_scan = (N_NODES + 1023) / 1024;   // 98

    stats_partial_k<<<NB_STATS, 256, 0, stream>>>(x, part, deg, cnt);
    normalize_k<<<1024, 256, 0, stream>>>(x, part, h0,
            Wl2, Wr2, W1, W2, Wpk2, Wpk1, W2pk, ei, deg);
    alloc_k<<<nb_scan, 256, 0, stream>>>(deg, rowptr, cnt);
    scatter_k<<<(N_EDGES + 255) / 256, 256, 0, stream>>>(ei, rowptr, csr);

    agg1conv1_k<<<(N_NODES + 255) / 256, 256, 0, stream>>>(h0, rowptr, deg, csr,
            Wl1, bl1, Wr1, Xb);
    agg2_k<<<N_NODES / 16, 256, 0, stream>>>(Xb, rowptr, deg, csr);
    conv2mlp_k<<<256, 512, 0, stream>>>(Xb, Wpk2, bl2, Wpk1, b1, W2pk, b2,
            (float*)d_out);
}